// Round 16
// baseline (159.277 us; speedup 1.0000x reference)
//
#include <hip/hip_runtime.h>

#define B_ 2
#define S_ 2048
#define D_ 1024
#define H_ 16
#define HD_ 64

typedef unsigned short u16;
typedef short bf16x8 __attribute__((ext_vector_type(8)));
typedef float f32x4 __attribute__((ext_vector_type(4)));

union FragU { bf16x8 v; u16 u[8]; uint2 d2[2]; unsigned w[4]; uint4 q; };

__device__ __forceinline__ u16 f2bf(float f) {
  unsigned int x = __builtin_bit_cast(unsigned int, f);
  x += 0x7fffu + ((x >> 16) & 1u);   // round-to-nearest-even
  return (u16)(x >> 16);
}

__device__ __forceinline__ float fexp2(float x) {
  return __builtin_amdgcn_exp2f(x);   // raw v_exp_f32
}

// async global -> LDS, 16B per lane. dest = wave-uniform base + lane*16.
__device__ __forceinline__ void g2l(const void* g, void* l) {
  __builtin_amdgcn_global_load_lds(
      (const __attribute__((address_space(1))) unsigned int*)g,
      (__attribute__((address_space(3))) unsigned int*)l, 16, 0, 0);
}

#define MFMA16(a, b, c) __builtin_amdgcn_mfma_f32_16x16x32_bf16(a, b, c, 0, 0, 0)

// k-interleave within 32-group: p = ((m&15)>>2)*8 + ((m>>4)<<2) + (m&3)
#define KPERM(m) ((((m) & 15) >> 2) * 8 + (((m) >> 4) << 2) + ((m) & 3))

// ---------------------------------------------------------------------------
// prep v3 (unchanged): W -> WT bf16, k-interleaved. 192 blocks.
// ---------------------------------------------------------------------------
__global__ __launch_bounds__(256) void prep_kernel(
    const float* __restrict__ Wq, const float* __restrict__ Wk,
    const float* __restrict__ Wv, u16* __restrict__ WT)
{
  const int blk = blockIdx.x;
  const int z = blk >> 6, h = (blk >> 2) & 15, qtr = blk & 3;
  const float* src = ((z == 0) ? Wq : (z == 1) ? Wk : Wv) + (size_t)h * D_ * HD_;
  u16* dst = WT + (size_t)z * D_ * D_ + (size_t)h * HD_ * D_;
  const int tid = threadIdx.x;
  const int n = tid & 63, kh = tid >> 6;
  #pragma unroll
  for (int k32 = qtr * 2; k32 < qtr * 2 + 2; ++k32) {
    const int kbase = kh * 256 + k32 * 32;
    union { u16 u[32]; uint4 q[4]; } pk;
    #pragma unroll
    for (int m = 0; m < 32; ++m)
      pk.u[KPERM(m)] = f2bf(src[(size_t)(kbase + m) * HD_ + n]);
    #pragma unroll
    for (int j = 0; j < 4; ++j)
      *(uint4*)(dst + (size_t)n * D_ + kbase + j * 8) = pk.q[j];
  }
}

// ---------------------------------------------------------------------------
// proj v10 (r13 version, reverted from the regressed 128x128 v11):
// 64x128 tile, BK=64, A reg-staged from f32 X, B via global_load_lds.
// ---------------------------------------------------------------------------
__global__ __launch_bounds__(256) void proj_kernel(
    const float* __restrict__ Xq, const float* __restrict__ Xk, const float* __restrict__ Xv,
    const u16* __restrict__ WT,
    const float* __restrict__ bq, const float* __restrict__ bk, const float* __restrict__ bv,
    u16* __restrict__ qo, u16* __restrict__ ko, u16* __restrict__ vo)
{
  const int z = blockIdx.z;
  const int rowb = blockIdx.x;
  const int col  = blockIdx.y;
  const float* X  = (z == 0) ? Xq : (z == 1) ? Xk : Xv;
  const float* Bb = (z == 0) ? bq : (z == 1) ? bk : bv;
  u16* out = (z == 0) ? qo : (z == 1) ? ko : vo;
  const float scale = (z == 0) ? 0.125f * 1.44269504f : 1.0f;

  const int tid = threadIdx.x;
  const int l = tid & 63, w = tid >> 6;
  const int g = l >> 4, lr = l & 15;
  const int wm = w >> 1, wn = w & 1;

  __shared__ u16 As_[2][64 * 64];
  __shared__ u16 Bs_[2][128 * 64];

  const char* Wb = (const char*)(WT + (size_t)z * D_ * D_ + (size_t)col * 128 * D_);

  int bOff[4], bLds[4];
  #pragma unroll
  for (int i = 0; i < 4; ++i) {
    const int br = w * 32 + i * 8 + (l >> 3);
    bOff[i] = br * 2048 + (((l & 7) * 16) ^ ((br & 7) << 4));
    bLds[i] = (w * 4 + i) * 1024;
  }

  const int arow  = tid >> 2;
  const int aksub = (tid >> 1) & 1;
  const int ag0   = (tid & 1) * 2;
  const float* aSrc = X + (size_t)(rowb * 64 + arow) * D_ + aksub * 32 + ag0 * 4;
  const int asw = (arow & 7) << 4;
  const int aw0 = arow * 128 + ((aksub * 64 + ag0 * 16) ^ asw);
  const int aw1 = arow * 128 + ((aksub * 64 + (ag0 + 1) * 16) ^ asw);

  float4 a0, a1, a2, a3;

#define ALOAD(k0)                                                              \
  {                                                                            \
    const float* s = aSrc + (k0);                                              \
    a0 = *(const float4*)s;        a1 = *(const float4*)(s + 16);              \
    a2 = *(const float4*)(s + 4);  a3 = *(const float4*)(s + 20);              \
  }

#define AWRITE(buf)                                                            \
  {                                                                            \
    FragU t0, t1;                                                              \
    asm("v_cvt_pk_bf16_f32 %0, %1, %2" : "=v"(t0.w[0]) : "v"(a0.x), "v"(a0.y));\
    asm("v_cvt_pk_bf16_f32 %0, %1, %2" : "=v"(t0.w[1]) : "v"(a0.z), "v"(a0.w));\
    asm("v_cvt_pk_bf16_f32 %0, %1, %2" : "=v"(t0.w[2]) : "v"(a1.x), "v"(a1.y));\
    asm("v_cvt_pk_bf16_f32 %0, %1, %2" : "=v"(t0.w[3]) : "v"(a1.z), "v"(a1.w));\
    asm("v_cvt_pk_bf16_f32 %0, %1, %2" : "=v"(t1.w[0]) : "v"(a2.x), "v"(a2.y));\
    asm("v_cvt_pk_bf16_f32 %0, %1, %2" : "=v"(t1.w[1]) : "v"(a2.z), "v"(a2.w));\
    asm("v_cvt_pk_bf16_f32 %0, %1, %2" : "=v"(t1.w[2]) : "v"(a3.x), "v"(a3.y));\
    asm("v_cvt_pk_bf16_f32 %0, %1, %2" : "=v"(t1.w[3]) : "v"(a3.z), "v"(a3.w));\
    *(uint4*)((char*)As_[buf] + aw0) = t0.q;                                   \
    *(uint4*)((char*)As_[buf] + aw1) = t1.q;                                   \
  }

  ALOAD(0);
  AWRITE(0);
  #pragma unroll
  for (int i = 0; i < 4; ++i) g2l(Wb + bOff[i], (char*)Bs_[0] + bLds[i]);
  __syncthreads();

  const f32x4 zero = {0.f, 0.f, 0.f, 0.f};
  f32x4 acc[2][4];
  #pragma unroll
  for (int mt = 0; mt < 2; ++mt)
    #pragma unroll
    for (int nt = 0; nt < 4; ++nt) acc[mt][nt] = zero;

  for (int ks = 0; ks < 16; ++ks) {
    const int cur = ks & 1;
    if (ks < 15) {
      ALOAD((ks + 1) * 64);
      #pragma unroll
      for (int i = 0; i < 4; ++i)
        g2l(Wb + bOff[i] + (ks + 1) * 128, (char*)Bs_[cur ^ 1] + bLds[i]);
    }

    const char* Ac = (const char*)As_[cur];
    const char* Bc = (const char*)Bs_[cur];
    #pragma unroll
    for (int ksub = 0; ksub < 2; ++ksub) {
      FragU aF[2], bF[4];
      #pragma unroll
      for (int mt = 0; mt < 2; ++mt) {
        const int row = wm * 32 + mt * 16 + lr;
        aF[mt].v = *(const bf16x8*)(Ac + row * 128 +
                    ((ksub * 64 + g * 16) ^ ((row & 7) << 4)));
      }
      #pragma unroll
      for (int nt = 0; nt < 4; ++nt) {
        const int row = wn * 64 + nt * 16 + lr;
        bF[nt].v = *(const bf16x8*)(Bc + row * 128 +
                    ((ksub * 64 + g * 16) ^ ((row & 7) << 4)));
      }
      __builtin_amdgcn_s_setprio(1);
      #pragma unroll
      for (int mt = 0; mt < 2; ++mt)
        #pragma unroll
        for (int nt = 0; nt < 4; ++nt)
          acc[mt][nt] = MFMA16(aF[mt].v, bF[nt].v, acc[mt][nt]);
      __builtin_amdgcn_s_setprio(0);
    }

    if (ks < 15) AWRITE(cur ^ 1);
    __syncthreads();
  }

  #pragma unroll
  for (int nt = 0; nt < 4; ++nt) {
    const int ng = col * 128 + wn * 64 + nt * 16 + lr;
    const float bias = Bb[ng];
    const int h = ng >> 6, n = ng & 63;
    const int dperm = (n & 32) + ((n & 15) >> 2) * 8 + ((n & 16) >> 4) * 4 + (n & 3);
    #pragma unroll
    for (int mt = 0; mt < 2; ++mt) {
      const int R = rowb * 64 + wm * 32 + mt * 16 + g * 4;
      const int b = R >> 11, s0 = R & (S_ - 1);
      if (z < 2) {
        #pragma unroll
        for (int r = 0; r < 4; ++r)
          out[(((size_t)b * H_ + h) * S_ + s0 + r) * HD_ + dperm] =
              f2bf((acc[mt][nt][r] + bias) * scale);
      } else {
        const int a = (s0 >> 2) & 7;
        const int s0p = (s0 & ~31) + ((2 * (a & 3) + (a >> 2)) << 2);
        union { u16 u[4]; uint2 d; } pk;
        #pragma unroll
        for (int r = 0; r < 4; ++r) pk.u[r] = f2bf(acc[mt][nt][r] + bias);
        *(uint2*)(out + (((size_t)b * H_ + h) * HD_ + n) * S_ + s0p) = pk.d;
      }
    }
  }
#undef ALOAD
#undef AWRITE
}

// ---------------------------------------------------------------------------
// Flash attention v11: KVBLK=128 (16 iters, half the barriers of v9),
// double-buffered K/V LDS, one barrier/iter, per-lane l, defer-max, v_exp.
// K LDS: [128][144B]; V LDS: [64][272B] (256B data + 16B pad).
// ---------------------------------------------------------------------------
__global__ __launch_bounds__(256) void attn_kernel(
    const u16* __restrict__ q, const u16* __restrict__ k,
    const u16* __restrict__ vt, u16* __restrict__ attP, float* __restrict__ lrow)
{
  const int bid = blockIdx.x;
  const int xcd = bid & 7;
  const int t1 = bid >> 3;
  const int qt = t1 & 15;
  const int bh = ((t1 >> 4) << 3) | xcd;

  const int tid = threadIdx.x;
  const int l = tid & 63, w = tid >> 6;
  const int g = l >> 4, lr = l & 15;
  const int qbase = qt * 128 + w * 32;

  #define KBUF 18432   // 128*144
  #define VBUF 17408   // 64*272
  __shared__ __align__(16) char Ksm[2 * KBUF];
  __shared__ __align__(16) char Vsm[2 * VBUF];

  FragU qf[2][2];
  #pragma unroll
  for (int qg = 0; qg < 2; ++qg) {
    const char* qrow = (const char*)(q + ((size_t)bh * S_ + qbase + qg * 16 + lr) * HD_);
    qf[qg][0].v = *(const bf16x8*)(qrow + g * 16);
    qf[qg][1].v = *(const bf16x8*)(qrow + 64 + g * 16);
  }

  const char* kByte = (const char*)(k + (size_t)bh * S_ * HD_);
  const char* vByte = (const char*)(vt + (size_t)bh * HD_ * S_);

  // staging: 4 K-chunks + 4 V-chunks of 16B per thread (tile = 16 KB each)
  char* kDst[4]; char* vDst[4];
  const char* kSrc[4]; const char* vSrc[4];
  #pragma unroll
  for (int j = 0; j < 4; ++j) {
    const int off = tid * 16 + j * 4096;
    const int kr = off >> 7, kc = off & 127;
    kDst[j] = Ksm + kr * 144 + kc;
    kSrc[j] = kByte + off;                       // + t0*128
    const int vr = off >> 8, vc = off & 255;
    vDst[j] = Vsm + vr * 272 + vc;
    vSrc[j] = vByte + (size_t)vr * (S_ * 2) + vc;   // + t0*2
  }

  uint4 kR[4], vR[4];
  #pragma unroll
  for (int j = 0; j < 4; ++j) {
    kR[j] = *(const uint4*)kSrc[j];
    vR[j] = *(const uint4*)vSrc[j];
  }
  #pragma unroll
  for (int j = 0; j < 4; ++j) {
    *(uint4*)kDst[j] = kR[j];
    *(uint4*)vDst[j] = vR[j];
  }
  __syncthreads();

  const f32x4 zero = {0.f, 0.f, 0.f, 0.f};
  f32x4 accO[2][4] = {{zero, zero, zero, zero}, {zero, zero, zero, zero}};
  float m_[2] = {-3e38f, -3e38f};
  float l_[2] = {0.f, 0.f};

  const char* kfb = Ksm + lr * 144 + g * 16;
  const char* vfb = Vsm + lr * 272 + g * 16;

  for (int t0 = 0; t0 < S_; t0 += 128) {
    const int cur = (t0 >> 7) & 1;
    const bool hasNext = (t0 + 128) < S_;
    if (hasNext) {
      #pragma unroll
      for (int j = 0; j < 4; ++j) {
        kR[j] = *(const uint4*)(kSrc[j] + (t0 + 128) * 128);
        vR[j] = *(const uint4*)(vSrc[j] + (t0 + 128) * 2);
      }
    }
    const char* kfbc = kfb + cur * KBUF;
    const char* vfbc = vfb + cur * VBUF;

    // ---- QK^T: sc[qg][ct] covers t = t0 + ct*16 + {4g..4g+3} ----
    f32x4 sc[2][8];
    #pragma unroll
    for (int qg = 0; qg < 2; ++qg)
      #pragma unroll
      for (int ct = 0; ct < 8; ++ct) sc[qg][ct] = zero;
    __builtin_amdgcn_s_setprio(1);
    #pragma unroll
    for (int ct = 0; ct < 8; ++ct) {
      FragU kf0, kf1;
      kf0.v = *(const bf16x8*)(kfbc + ct * 2304);
      kf1.v = *(const bf16x8*)(kfbc + ct * 2304 + 64);
      sc[0][ct] = MFMA16(kf0.v, qf[0][0].v, sc[0][ct]);
      sc[0][ct] = MFMA16(kf1.v, qf[0][1].v, sc[0][ct]);
      sc[1][ct] = MFMA16(kf0.v, qf[1][0].v, sc[1][ct]);
      sc[1][ct] = MFMA16(kf1.v, qf[1][1].v, sc[1][ct]);
    }
    __builtin_amdgcn_s_setprio(0);

    // ---- per-lane local max (32 scores per qg) ----
    float lmax[2];
    #pragma unroll
    for (int qg = 0; qg < 2; ++qg) {
      float a[8];
      #pragma unroll
      for (int ct = 0; ct < 8; ++ct)
        a[ct] = fmaxf(fmaxf(sc[qg][ct][0], sc[qg][ct][1]),
                      fmaxf(sc[qg][ct][2], sc[qg][ct][3]));
      float m01 = fmaxf(a[0], a[1]), m23 = fmaxf(a[2], a[3]);
      float m45 = fmaxf(a[4], a[5]), m67 = fmaxf(a[6], a[7]);
      lmax[qg] = fmaxf(fmaxf(m01, m23), fmaxf(m45, m67));
    }
    if (__any((lmax[0] - m_[0] > 8.f) || (lmax[1] - m_[1] > 8.f))) {
      #pragma unroll
      for (int qg = 0; qg < 2; ++qg) {
        float mm = lmax[qg];
        mm = fmaxf(mm, __shfl_xor(mm, 16));
        mm = fmaxf(mm, __shfl_xor(mm, 32));
        const float mn = fmaxf(m_[qg], mm);
        const float al = fexp2(m_[qg] - mn);
        m_[qg] = mn;
        l_[qg] *= al;
        float alr[4];
        #pragma unroll
        for (int r = 0; r < 4; ++r) alr[r] = __shfl(al, g * 4 + r);
        #pragma unroll
        for (int dt = 0; dt < 4; ++dt)
          #pragma unroll
          for (int r = 0; r < 4; ++r) accO[qg][dt][r] *= alr[r];
      }
    }

    // ---- exp + per-lane partial sum + pack ----
    FragU pf[2][4];
    #pragma unroll
    for (int qg = 0; qg < 2; ++qg) {
      #pragma unroll
      for (int ct = 0; ct < 8; ++ct)
        #pragma unroll
        for (int r = 0; r < 4; ++r)
          sc[qg][ct][r] = fexp2(sc[qg][ct][r] - m_[qg]);
      float ssum = 0.f;
      #pragma unroll
      for (int ct = 0; ct < 8; ++ct)
        ssum += (sc[qg][ct][0] + sc[qg][ct][1]) + (sc[qg][ct][2] + sc[qg][ct][3]);
      l_[qg] += ssum;
      #pragma unroll
      for (int tc = 0; tc < 4; ++tc) {
        asm("v_cvt_pk_bf16_f32 %0, %1, %2" : "=v"(pf[qg][tc].w[0]) : "v"(sc[qg][2*tc][0]),   "v"(sc[qg][2*tc][1]));
        asm("v_cvt_pk_bf16_f32 %0, %1, %2" : "=v"(pf[qg][tc].w[1]) : "v"(sc[qg][2*tc][2]),   "v"(sc[qg][2*tc][3]));
        asm("v_cvt_pk_bf16_f32 %0, %1, %2" : "=v"(pf[qg][tc].w[2]) : "v"(sc[qg][2*tc+1][0]), "v"(sc[qg][2*tc+1][1]));
        asm("v_cvt_pk_bf16_f32 %0, %1, %2" : "=v"(pf[qg][tc].w[3]) : "v"(sc[qg][2*tc+1][2]), "v"(sc[qg][2*tc+1][3]));
      }
    }

    // ---- PV: accO[qg][dt] += sum_tc P(tc) @ V(tc) ----
    __builtin_amdgcn_s_setprio(1);
    #pragma unroll
    for (int dt = 0; dt < 4; ++dt) {
      FragU vf[4];
      #pragma unroll
      for (int tc = 0; tc < 4; ++tc)
        vf[tc].v = *(const bf16x8*)(vfbc + dt * 4352 + tc * 64);
      #pragma unroll
      for (int tc = 0; tc < 4; ++tc) {
        accO[0][dt] = MFMA16(pf[0][tc].v, vf[tc].v, accO[0][dt]);
        accO[1][dt] = MFMA16(pf[1][tc].v, vf[tc].v, accO[1][dt]);
      }
    }
    __builtin_amdgcn_s_setprio(0);

    if (hasNext) {
      const int kb = ((cur ^ 1) ? KBUF : 0);
      const int vb = ((cur ^ 1) ? VBUF : 0);
      #pragma unroll
      for (int j = 0; j < 4; ++j) {
        *(uint4*)(kDst[j] + kb) = kR[j];
        *(uint4*)(vDst[j] + vb) = vR[j];
      }
    }
    __syncthreads();
  }

  const int b = bh >> 4, h = bh & (H_ - 1);
  u16* basep = attP + (size_t)b * S_ * D_;
  #pragma unroll
  for (int qg = 0; qg < 2; ++qg) {
    float lt = l_[qg];
    lt += __shfl_xor(lt, 16);
    lt += __shfl_xor(lt, 32);
    #pragma unroll
    for (int r = 0; r < 4; ++r) {
      const int s = qbase + qg * 16 + g * 4 + r;
      u16* op = basep + (size_t)s * D_ + h * HD_;
      #pragma unroll
      for (int dt = 0; dt < 4; ++dt) op[dt * 16 + lr] = f2bf(accO[qg][dt][r]);
    }
    if (g == 0)
      lrow[((size_t)b * H_ + h) * S_ + qbase + qg * 16 + lr] = lt;
  }
  #undef KBUF
  #undef VBUF
}

// ---------------------------------------------------------------------------
// combine (divide by l) + LayerNorm, bf16 partial input.
// ---------------------------------------------------------------------------
__global__ __launch_bounds__(256) void combine_ln_kernel(
    const u16* __restrict__ attP, const float* __restrict__ lrow,
    const float* __restrict__ gamma, const float* __restrict__ beta,
    float* __restrict__ out)
{
  const int row = blockIdx.x;          // b*S + s
  const int b = row >> 11, s = row & (S_ - 1);
  const int tid = threadIdx.x;
  const int h = tid >> 4;

  const float inv = 1.0f / lrow[((size_t)b * H_ + h) * S_ + s];
  union { uint2 d; u16 u[4]; } raw;
  raw.d = ((const uint2*)(attP + (size_t)row * D_))[tid];
  float4 x;
  x.x = __builtin_bit_cast(float, (unsigned)raw.u[0] << 16) * inv;
  x.y = __builtin_bit_cast(float, (unsigned)raw.u[1] << 16) * inv;
  x.z = __builtin_bit_cast(float, (unsigned)raw.u[2] << 16) * inv;
  x.w = __builtin_bit_cast(float, (unsigned)raw.u[3] << 16) * inv;

  float sm = x.x + x.y + x.z + x.w;
  float sq = x.x * x.x + x.y * x.y + x.z * x.z + x.w * x.w;
  #pragma unroll
  for (int j = 1; j < 64; j <<= 1) { sm += __shfl_xor(sm, j); sq += __shfl_xor(sq, j); }
  __shared__ float ls[4], lq[4];
  const int w = tid >> 6;
  if ((tid & 63) == 0) { ls[w] = sm; lq[w] = sq; }
  __syncthreads();
  if (tid == 0) {
    ls[0] = ls[0] + ls[1] + ls[2] + ls[3];
    lq[0] = lq[0] + lq[1] + lq[2] + lq[3];
  }
  __syncthreads();
  const float mean = ls[0] * (1.f / D_);
  const float var  = lq[0] * (1.f / D_) - mean * mean;
  const float rs = rsqrtf(var + 1e-5f);
  const float4 gv = ((const float4*)gamma)[tid];
  const float4 bv = ((const float4*)beta)[tid];
  float4 o;
  o.x = (x.x - mean) * rs * gv.x + bv.x;
  o.y = (x.y - mean) * rs * gv.y + bv.y;
  o.z = (x.z - mean) * rs * gv.z + bv.z;
  o.w = (x.w - mean) * rs * gv.w + bv.w;
  ((float4*)(out + (size_t)row * D_))[tid] = o;
}

extern "C" void kernel_launch(void* const* d_in, const int* in_sizes, int n_in,
                              void* d_out, int out_size, void* d_ws, size_t ws_size,
                              hipStream_t stream) {
  const float* queries = (const float*)d_in[0];
  const float* keys    = (const float*)d_in[1];
  const float* values  = (const float*)d_in[2];
  const float* Wq = (const float*)d_in[3];
  const float* bq = (const float*)d_in[4];
  const float* Wk = (const float*)d_in[5];
  const float* bk = (const float*)d_in[6];
  const float* Wv = (const float*)d_in[7];
  const float* bv = (const float*)d_in[8];
  const float* gamma = (const float*)d_in[9];
  const float* beta  = (const float*)d_in[10];
  float* out = (float*)d_out;

  const size_t PER = (size_t)B_ * H_ * S_ * HD_;          // 4,194,304 elems
  u16* q_ws  = (u16*)d_ws;                                // 8 MB
  u16* k_ws  = q_ws + PER;                                // 8 MB
  u16* vt_ws = k_ws + PER;                                // 8 MB
  u16* WT   = vt_ws + PER;                                // 6 MB, dead after proj
  u16* attP = vt_ws + PER;                                // aliases WT (8 MB)
  const size_t NOUT = (size_t)B_ * S_ * D_;
  float* lrow = (float*)(attP + NOUT);

  prep_kernel<<<dim3(192), 256, 0, stream>>>(Wq, Wk, Wv, WT);
  proj_kernel<<<dim3(64, 8, 3), 256, 0, stream>>>(
      queries, keys, values, WT, bq, bk, bv, q_ws, k_ws, vt_ws);
  attn_kernel<<<dim3(512), 256, 0, stream>>>(q_ws, k_ws, vt_ws, attP, lrow);
  combine_ln_kernel<<<dim3(4096), 256, 0, stream>>>(attP, lrow, gamma, beta, out);
}

// Round 17
// 123.983 us; speedup vs baseline: 1.2847x; 1.2847x over previous
//
#include <hip/hip_runtime.h>

#define B_ 2
#define S_ 2048
#define D_ 1024
#define H_ 16
#define HD_ 64

typedef unsigned short u16;
typedef short bf16x8 __attribute__((ext_vector_type(8)));
typedef float f32x4 __attribute__((ext_vector_type(4)));

union FragU { bf16x8 v; u16 u[8]; uint2 d2[2]; unsigned w[4]; uint4 q; };

__device__ __forceinline__ u16 f2bf(float f) {
  unsigned int x = __builtin_bit_cast(unsigned int, f);
  x += 0x7fffu + ((x >> 16) & 1u);   // round-to-nearest-even
  return (u16)(x >> 16);
}

__device__ __forceinline__ float fexp2(float x) {
  return __builtin_amdgcn_exp2f(x);   // raw v_exp_f32
}

// async global -> LDS, 16B per lane. dest = wave-uniform base + lane*16.
__device__ __forceinline__ void g2l(const void* g, void* l) {
  __builtin_amdgcn_global_load_lds(
      (const __attribute__((address_space(1))) unsigned int*)g,
      (__attribute__((address_space(3))) unsigned int*)l, 16, 0, 0);
}

#define MFMA16(a, b, c) __builtin_amdgcn_mfma_f32_16x16x32_bf16(a, b, c, 0, 0, 0)

// k-interleave within 32-group: p = ((m&15)>>2)*8 + ((m>>4)<<2) + (m&3)
#define KPERM(m) ((((m) & 15) >> 2) * 8 + (((m) >> 4) << 2) + ((m) & 3))

// ---------------------------------------------------------------------------
// prep v3: W -> WT bf16, k-interleaved. 192 blocks.
// ---------------------------------------------------------------------------
__global__ __launch_bounds__(256) void prep_kernel(
    const float* __restrict__ Wq, const float* __restrict__ Wk,
    const float* __restrict__ Wv, u16* __restrict__ WT)
{
  const int blk = blockIdx.x;
  const int z = blk >> 6, h = (blk >> 2) & 15, qtr = blk & 3;
  const float* src = ((z == 0) ? Wq : (z == 1) ? Wk : Wv) + (size_t)h * D_ * HD_;
  u16* dst = WT + (size_t)z * D_ * D_ + (size_t)h * HD_ * D_;
  const int tid = threadIdx.x;
  const int n = tid & 63, kh = tid >> 6;
  #pragma unroll
  for (int k32 = qtr * 2; k32 < qtr * 2 + 2; ++k32) {
    const int kbase = kh * 256 + k32 * 32;
    union { u16 u[32]; uint4 q[4]; } pk;
    #pragma unroll
    for (int m = 0; m < 32; ++m)
      pk.u[KPERM(m)] = f2bf(src[(size_t)(kbase + m) * HD_ + n]);
    #pragma unroll
    for (int j = 0; j < 4; ++j)
      *(uint4*)(dst + (size_t)n * D_ + kbase + j * 8) = pk.q[j];
  }
}

// ---------------------------------------------------------------------------
// proj v10 (r13): 64x128 tile, BK=64, A reg-staged from f32 X (loads at iter
// top, cvt_pk + swizzled ds_write before barrier), B via global_load_lds.
// ---------------------------------------------------------------------------
__global__ __launch_bounds__(256) void proj_kernel(
    const float* __restrict__ Xq, const float* __restrict__ Xk, const float* __restrict__ Xv,
    const u16* __restrict__ WT,
    const float* __restrict__ bq, const float* __restrict__ bk, const float* __restrict__ bv,
    u16* __restrict__ qo, u16* __restrict__ ko, u16* __restrict__ vo)
{
  const int z = blockIdx.z;
  const int rowb = blockIdx.x;
  const int col  = blockIdx.y;
  const float* X  = (z == 0) ? Xq : (z == 1) ? Xk : Xv;
  const float* Bb = (z == 0) ? bq : (z == 1) ? bk : bv;
  u16* out = (z == 0) ? qo : (z == 1) ? ko : vo;
  const float scale = (z == 0) ? 0.125f * 1.44269504f : 1.0f;

  const int tid = threadIdx.x;
  const int l = tid & 63, w = tid >> 6;
  const int g = l >> 4, lr = l & 15;
  const int wm = w >> 1, wn = w & 1;

  __shared__ u16 As_[2][64 * 64];
  __shared__ u16 Bs_[2][128 * 64];

  const char* Wb = (const char*)(WT + (size_t)z * D_ * D_ + (size_t)col * 128 * D_);

  int bOff[4], bLds[4];
  #pragma unroll
  for (int i = 0; i < 4; ++i) {
    const int br = w * 32 + i * 8 + (l >> 3);
    bOff[i] = br * 2048 + (((l & 7) * 16) ^ ((br & 7) << 4));
    bLds[i] = (w * 4 + i) * 1024;
  }

  const int arow  = tid >> 2;
  const int aksub = (tid >> 1) & 1;
  const int ag0   = (tid & 1) * 2;
  const float* aSrc = X + (size_t)(rowb * 64 + arow) * D_ + aksub * 32 + ag0 * 4;
  const int asw = (arow & 7) << 4;
  const int aw0 = arow * 128 + ((aksub * 64 + ag0 * 16) ^ asw);
  const int aw1 = arow * 128 + ((aksub * 64 + (ag0 + 1) * 16) ^ asw);

  float4 a0, a1, a2, a3;

#define ALOAD(k0)                                                              \
  {                                                                            \
    const float* s = aSrc + (k0);                                              \
    a0 = *(const float4*)s;        a1 = *(const float4*)(s + 16);              \
    a2 = *(const float4*)(s + 4);  a3 = *(const float4*)(s + 20);              \
  }

#define AWRITE(buf)                                                            \
  {                                                                            \
    FragU t0, t1;                                                              \
    asm("v_cvt_pk_bf16_f32 %0, %1, %2" : "=v"(t0.w[0]) : "v"(a0.x), "v"(a0.y));\
    asm("v_cvt_pk_bf16_f32 %0, %1, %2" : "=v"(t0.w[1]) : "v"(a0.z), "v"(a0.w));\
    asm("v_cvt_pk_bf16_f32 %0, %1, %2" : "=v"(t0.w[2]) : "v"(a1.x), "v"(a1.y));\
    asm("v_cvt_pk_bf16_f32 %0, %1, %2" : "=v"(t0.w[3]) : "v"(a1.z), "v"(a1.w));\
    asm("v_cvt_pk_bf16_f32 %0, %1, %2" : "=v"(t1.w[0]) : "v"(a2.x), "v"(a2.y));\
    asm("v_cvt_pk_bf16_f32 %0, %1, %2" : "=v"(t1.w[1]) : "v"(a2.z), "v"(a2.w));\
    asm("v_cvt_pk_bf16_f32 %0, %1, %2" : "=v"(t1.w[2]) : "v"(a3.x), "v"(a3.y));\
    asm("v_cvt_pk_bf16_f32 %0, %1, %2" : "=v"(t1.w[3]) : "v"(a3.z), "v"(a3.w));\
    *(uint4*)((char*)As_[buf] + aw0) = t0.q;                                   \
    *(uint4*)((char*)As_[buf] + aw1) = t1.q;                                   \
  }

  ALOAD(0);
  AWRITE(0);
  #pragma unroll
  for (int i = 0; i < 4; ++i) g2l(Wb + bOff[i], (char*)Bs_[0] + bLds[i]);
  __syncthreads();

  const f32x4 zero = {0.f, 0.f, 0.f, 0.f};
  f32x4 acc[2][4];
  #pragma unroll
  for (int mt = 0; mt < 2; ++mt)
    #pragma unroll
    for (int nt = 0; nt < 4; ++nt) acc[mt][nt] = zero;

  for (int ks = 0; ks < 16; ++ks) {
    const int cur = ks & 1;
    if (ks < 15) {
      ALOAD((ks + 1) * 64);
      #pragma unroll
      for (int i = 0; i < 4; ++i)
        g2l(Wb + bOff[i] + (ks + 1) * 128, (char*)Bs_[cur ^ 1] + bLds[i]);
    }

    const char* Ac = (const char*)As_[cur];
    const char* Bc = (const char*)Bs_[cur];
    #pragma unroll
    for (int ksub = 0; ksub < 2; ++ksub) {
      FragU aF[2], bF[4];
      #pragma unroll
      for (int mt = 0; mt < 2; ++mt) {
        const int row = wm * 32 + mt * 16 + lr;
        aF[mt].v = *(const bf16x8*)(Ac + row * 128 +
                    ((ksub * 64 + g * 16) ^ ((row & 7) << 4)));
      }
      #pragma unroll
      for (int nt = 0; nt < 4; ++nt) {
        const int row = wn * 64 + nt * 16 + lr;
        bF[nt].v = *(const bf16x8*)(Bc + row * 128 +
                    ((ksub * 64 + g * 16) ^ ((row & 7) << 4)));
      }
      __builtin_amdgcn_s_setprio(1);
      #pragma unroll
      for (int mt = 0; mt < 2; ++mt)
        #pragma unroll
        for (int nt = 0; nt < 4; ++nt)
          acc[mt][nt] = MFMA16(aF[mt].v, bF[nt].v, acc[mt][nt]);
      __builtin_amdgcn_s_setprio(0);
    }

    if (ks < 15) AWRITE(cur ^ 1);
    __syncthreads();
  }

  #pragma unroll
  for (int nt = 0; nt < 4; ++nt) {
    const int ng = col * 128 + wn * 64 + nt * 16 + lr;
    const float bias = Bb[ng];
    const int h = ng >> 6, n = ng & 63;
    const int dperm = (n & 32) + ((n & 15) >> 2) * 8 + ((n & 16) >> 4) * 4 + (n & 3);
    #pragma unroll
    for (int mt = 0; mt < 2; ++mt) {
      const int R = rowb * 64 + wm * 32 + mt * 16 + g * 4;
      const int b = R >> 11, s0 = R & (S_ - 1);
      if (z < 2) {
        #pragma unroll
        for (int r = 0; r < 4; ++r)
          out[(((size_t)b * H_ + h) * S_ + s0 + r) * HD_ + dperm] =
              f2bf((acc[mt][nt][r] + bias) * scale);
      } else {
        const int a = (s0 >> 2) & 7;
        const int s0p = (s0 & ~31) + ((2 * (a & 3) + (a >> 2)) << 2);
        union { u16 u[4]; uint2 d; } pk;
        #pragma unroll
        for (int r = 0; r < 4; ++r) pk.u[r] = f2bf(acc[mt][nt][r] + bias);
        *(uint2*)(out + (((size_t)b * H_ + h) * HD_ + n) * S_ + s0p) = pk.d;
      }
    }
  }
#undef ALOAD
#undef AWRITE
}

// ---------------------------------------------------------------------------
// Flash attention v9 (r13): KVBLK=64, double-buffered K/V LDS, one barrier
// per iter, per-lane l, defer-max, raw v_exp, bf16 partial output.
// ---------------------------------------------------------------------------
__global__ __launch_bounds__(256) void attn_kernel(
    const u16* __restrict__ q, const u16* __restrict__ k,
    const u16* __restrict__ vt, u16* __restrict__ attP, float* __restrict__ lrow)
{
  const int bid = blockIdx.x;
  const int xcd = bid & 7;
  const int t1 = bid >> 3;
  const int qt = t1 & 15;
  const int bh = ((t1 >> 4) << 3) | xcd;

  const int tid = threadIdx.x;
  const int l = tid & 63, w = tid >> 6;
  const int g = l >> 4, lr = l & 15;
  const int qbase = qt * 128 + w * 32;

  #define BUFSZ (64 * 144)
  __shared__ __align__(16) char Ksm[2 * BUFSZ];
  __shared__ __align__(16) char Vsm[2 * BUFSZ];

  FragU qf[2][2];
  #pragma unroll
  for (int qg = 0; qg < 2; ++qg) {
    const char* qrow = (const char*)(q + ((size_t)bh * S_ + qbase + qg * 16 + lr) * HD_);
    qf[qg][0].v = *(const bf16x8*)(qrow + g * 16);
    qf[qg][1].v = *(const bf16x8*)(qrow + 64 + g * 16);
  }

  const char* kByte = (const char*)(k + (size_t)bh * S_ * HD_);
  const char* vByte = (const char*)(vt + (size_t)bh * HD_ * S_);

  const int i0 = tid * 16, i1 = i0 + 4096;
  const int r0 = i0 >> 7, c0 = i0 & 127;
  const int r1 = i1 >> 7, c1 = i1 & 127;
  char* kD0 = Ksm + r0 * 144 + c0;
  char* kD1 = Ksm + r1 * 144 + c1;
  char* vD0 = Vsm + r0 * 144 + c0;
  char* vD1 = Vsm + r1 * 144 + c1;
  const char* kS0 = kByte + i0;
  const char* kS1 = kByte + i1;
  const char* vS0 = vByte + (size_t)r0 * (S_ * 2) + c0;
  const char* vS1 = vByte + (size_t)r1 * (S_ * 2) + c1;

  uint4 kA = *(const uint4*)kS0;
  uint4 kB = *(const uint4*)kS1;
  uint4 vA = *(const uint4*)vS0;
  uint4 vB = *(const uint4*)vS1;
  *(uint4*)kD0 = kA; *(uint4*)kD1 = kB;
  *(uint4*)vD0 = vA; *(uint4*)vD1 = vB;
  __syncthreads();

  const f32x4 zero = {0.f, 0.f, 0.f, 0.f};
  f32x4 accO[2][4] = {{zero, zero, zero, zero}, {zero, zero, zero, zero}};
  float m_[2] = {-3e38f, -3e38f};
  float l_[2] = {0.f, 0.f};

  const char* kfb = Ksm + lr * 144 + g * 16;
  const char* vfb = Vsm + lr * 144 + g * 16;

  for (int t0 = 0; t0 < S_; t0 += 64) {
    const int cur = (t0 >> 6) & 1;
    const bool hasNext = (t0 + 64) < S_;
    if (hasNext) {
      kA = *(const uint4*)(kS0 + (t0 + 64) * 128);
      kB = *(const uint4*)(kS1 + (t0 + 64) * 128);
      vA = *(const uint4*)(vS0 + (t0 + 64) * 2);
      vB = *(const uint4*)(vS1 + (t0 + 64) * 2);
    }
    const char* kfbc = kfb + cur * BUFSZ;
    const char* vfbc = vfb + cur * BUFSZ;

    f32x4 sc[2][4] = {{zero, zero, zero, zero}, {zero, zero, zero, zero}};
    __builtin_amdgcn_s_setprio(1);
    #pragma unroll
    for (int ct = 0; ct < 4; ++ct) {
      FragU kf0, kf1;
      kf0.v = *(const bf16x8*)(kfbc + ct * 2304);
      kf1.v = *(const bf16x8*)(kfbc + ct * 2304 + 64);
      sc[0][ct] = MFMA16(kf0.v, qf[0][0].v, sc[0][ct]);
      sc[0][ct] = MFMA16(kf1.v, qf[0][1].v, sc[0][ct]);
      sc[1][ct] = MFMA16(kf0.v, qf[1][0].v, sc[1][ct]);
      sc[1][ct] = MFMA16(kf1.v, qf[1][1].v, sc[1][ct]);
    }
    __builtin_amdgcn_s_setprio(0);

    float lmax[2];
    #pragma unroll
    for (int qg = 0; qg < 2; ++qg) {
      float a0 = fmaxf(fmaxf(sc[qg][0][0], sc[qg][0][1]), fmaxf(sc[qg][0][2], sc[qg][0][3]));
      float a1 = fmaxf(fmaxf(sc[qg][1][0], sc[qg][1][1]), fmaxf(sc[qg][1][2], sc[qg][1][3]));
      float a2 = fmaxf(fmaxf(sc[qg][2][0], sc[qg][2][1]), fmaxf(sc[qg][2][2], sc[qg][2][3]));
      float a3 = fmaxf(fmaxf(sc[qg][3][0], sc[qg][3][1]), fmaxf(sc[qg][3][2], sc[qg][3][3]));
      lmax[qg] = fmaxf(fmaxf(a0, a1), fmaxf(a2, a3));
    }
    if (__any((lmax[0] - m_[0] > 8.f) || (lmax[1] - m_[1] > 8.f))) {
      #pragma unroll
      for (int qg = 0; qg < 2; ++qg) {
        float mm = lmax[qg];
        mm = fmaxf(mm, __shfl_xor(mm, 16));
        mm = fmaxf(mm, __shfl_xor(mm, 32));
        const float mn = fmaxf(m_[qg], mm);
        const float al = fexp2(m_[qg] - mn);
        m_[qg] = mn;
        l_[qg] *= al;
        float alr[4];
        #pragma unroll
        for (int r = 0; r < 4; ++r) alr[r] = __shfl(al, g * 4 + r);
        #pragma unroll
        for (int dt = 0; dt < 4; ++dt)
          #pragma unroll
          for (int r = 0; r < 4; ++r) accO[qg][dt][r] *= alr[r];
      }
    }

    FragU pf[2][2];
    #pragma unroll
    for (int qg = 0; qg < 2; ++qg) {
      #pragma unroll
      for (int ct = 0; ct < 4; ++ct)
        #pragma unroll
        for (int r = 0; r < 4; ++r)
          sc[qg][ct][r] = fexp2(sc[qg][ct][r] - m_[qg]);
      float s0 = (sc[qg][0][0] + sc[qg][0][1]) + (sc[qg][0][2] + sc[qg][0][3]);
      float s1 = (sc[qg][1][0] + sc[qg][1][1]) + (sc[qg][1][2] + sc[qg][1][3]);
      float s2 = (sc[qg][2][0] + sc[qg][2][1]) + (sc[qg][2][2] + sc[qg][2][3]);
      float s3 = (sc[qg][3][0] + sc[qg][3][1]) + (sc[qg][3][2] + sc[qg][3][3]);
      l_[qg] += (s0 + s1) + (s2 + s3);
      #pragma unroll
      for (int tc = 0; tc < 2; ++tc) {
        asm("v_cvt_pk_bf16_f32 %0, %1, %2" : "=v"(pf[qg][tc].w[0]) : "v"(sc[qg][2*tc][0]),   "v"(sc[qg][2*tc][1]));
        asm("v_cvt_pk_bf16_f32 %0, %1, %2" : "=v"(pf[qg][tc].w[1]) : "v"(sc[qg][2*tc][2]),   "v"(sc[qg][2*tc][3]));
        asm("v_cvt_pk_bf16_f32 %0, %1, %2" : "=v"(pf[qg][tc].w[2]) : "v"(sc[qg][2*tc+1][0]), "v"(sc[qg][2*tc+1][1]));
        asm("v_cvt_pk_bf16_f32 %0, %1, %2" : "=v"(pf[qg][tc].w[3]) : "v"(sc[qg][2*tc+1][2]), "v"(sc[qg][2*tc+1][3]));
      }
    }

    __builtin_amdgcn_s_setprio(1);
    #pragma unroll
    for (int dt = 0; dt < 4; ++dt) {
      FragU vf0, vf1;
      vf0.v = *(const bf16x8*)(vfbc + dt * 2304);
      vf1.v = *(const bf16x8*)(vfbc + dt * 2304 + 64);
      accO[0][dt] = MFMA16(pf[0][0].v, vf0.v, accO[0][dt]);
      accO[0][dt] = MFMA16(pf[0][1].v, vf1.v, accO[0][dt]);
      accO[1][dt] = MFMA16(pf[1][0].v, vf0.v, accO[1][dt]);
      accO[1][dt] = MFMA16(pf[1][1].v, vf1.v, accO[1][dt]);
    }
    __builtin_amdgcn_s_setprio(0);

    if (hasNext) {
      const int nb = (cur ^ 1) * BUFSZ;
      *(uint4*)(kD0 + nb) = kA; *(uint4*)(kD1 + nb) = kB;
      *(uint4*)(vD0 + nb) = vA; *(uint4*)(vD1 + nb) = vB;
    }
    __syncthreads();
  }

  const int b = bh >> 4, h = bh & (H_ - 1);
  u16* basep = attP + (size_t)b * S_ * D_;
  #pragma unroll
  for (int qg = 0; qg < 2; ++qg) {
    float lt = l_[qg];
    lt += __shfl_xor(lt, 16);
    lt += __shfl_xor(lt, 32);
    #pragma unroll
    for (int r = 0; r < 4; ++r) {
      const int s = qbase + qg * 16 + g * 4 + r;
      u16* op = basep + (size_t)s * D_ + h * HD_;
      #pragma unroll
      for (int dt = 0; dt < 4; ++dt) op[dt * 16 + lr] = f2bf(accO[qg][dt][r]);
    }
    if (g == 0)
      lrow[((size_t)b * H_ + h) * S_ + qbase + qg * 16 + lr] = lt;
  }
  #undef BUFSZ
}

// ---------------------------------------------------------------------------
// combine (divide by l) + LayerNorm, bf16 partial input.
// ---------------------------------------------------------------------------
__global__ __launch_bounds__(256) void combine_ln_kernel(
    const u16* __restrict__ attP, const float* __restrict__ lrow,
    const float* __restrict__ gamma, const float* __restrict__ beta,
    float* __restrict__ out)
{
  const int row = blockIdx.x;          // b*S + s
  const int b = row >> 11, s = row & (S_ - 1);
  const int tid = threadIdx.x;
  const int h = tid >> 4;

  const float inv = 1.0f / lrow[((size_t)b * H_ + h) * S_ + s];
  union { uint2 d; u16 u[4]; } raw;
  raw.d = ((const uint2*)(attP + (size_t)row * D_))[tid];
  float4 x;
  x.x = __builtin_bit_cast(float, (unsigned)raw.u[0] << 16) * inv;
  x.y = __builtin_bit_cast(float, (unsigned)raw.u[1] << 16) * inv;
  x.z = __builtin_bit_cast(float, (unsigned)raw.u[2] << 16) * inv;
  x.w = __builtin_bit_cast(float, (unsigned)raw.u[3] << 16) * inv;

  float sm = x.x + x.y + x.z + x.w;
  float sq = x.x * x.x + x.y * x.y + x.z * x.z + x.w * x.w;
  #pragma unroll
  for (int j = 1; j < 64; j <<= 1) { sm += __shfl_xor(sm, j); sq += __shfl_xor(sq, j); }
  __shared__ float ls[4], lq[4];
  const int w = tid >> 6;
  if ((tid & 63) == 0) { ls[w] = sm; lq[w] = sq; }
  __syncthreads();
  if (tid == 0) {
    ls[0] = ls[0] + ls[1] + ls[2] + ls[3];
    lq[0] = lq[0] + lq[1] + lq[2] + lq[3];
  }
  __syncthreads();
  const float mean = ls[0] * (1.f / D_);
  const float var  = lq[0] * (1.f / D_) - mean * mean;
  const float rs = rsqrtf(var + 1e-5f);
  const float4 gv = ((const float4*)gamma)[tid];
  const float4 bv = ((const float4*)beta)[tid];
  float4 o;
  o.x = (x.x - mean) * rs * gv.x + bv.x;
  o.y = (x.y - mean) * rs * gv.y + bv.y;
  o.z = (x.z - mean) * rs * gv.z + bv.z;
  o.w = (x.w - mean) * rs * gv.w + bv.w;
  ((float4*)(out + (size_t)row * D_))[tid] = o;
}

extern "C" void kernel_launch(void* const* d_in, const int* in_sizes, int n_in,
                              void* d_out, int out_size, void* d_ws, size_t ws_size,
                              hipStream_t stream) {
  const float* queries = (const float*)d_in[0];
  const float* keys    = (const float*)d_in[1];
  const float* values  = (const float*)d_in[2];
  const float* Wq = (const float*)d_in[3];
  const float* bq = (const float*)d_in[4];
  const float* Wk = (const float*)d_in[5];
  const float* bk = (const float*)d_in[6];
  const float* Wv = (const float*)d_in[7];
  const float* bv = (const float*)d_in[8];
  const float* gamma = (const float*)d_in[9];
  const float* beta  = (const float*)d_in[10];
  float* out = (float*)d_out;

  const size_t PER = (size_t)B_ * H_ * S_ * HD_;          // 4,194,304 elems
  u16* q_ws  = (u16*)d_ws;                                // 8 MB
  u16* k_ws  = q_ws + PER;                                // 8 MB
  u16* vt_ws = k_ws + PER;                                // 8 MB
  u16* WT   = vt_ws + PER;                                // 6 MB, dead after proj
  u16* attP = vt_ws + PER;                                // aliases WT (8 MB)
  const size_t NOUT = (size_t)B_ * S_ * D_;
  float* lrow = (float*)(attP + NOUT);

  prep_kernel<<<dim3(192), 256, 0, stream>>>(Wq, Wk, Wv, WT);
  proj_kernel<<<dim3(64, 8, 3), 256, 0, stream>>>(
      queries, keys, values, WT, bq, bk, bv, q_ws, k_ws, vt_ws);
  attn_kernel<<<dim3(512), 256, 0, stream>>>(q_ws, k_ws, vt_ws, attP, lrow);
  combine_ln_kernel<<<dim3(4096), 256, 0, stream>>>(attP, lrow, gamma, beta, out);
}

// Round 18
// 117.302 us; speedup vs baseline: 1.3578x; 1.0570x over previous
//
#include <hip/hip_runtime.h>

#define B_ 2
#define S_ 2048
#define D_ 1024
#define H_ 16
#define HD_ 64

typedef unsigned short u16;
typedef short bf16x8 __attribute__((ext_vector_type(8)));
typedef float f32x4 __attribute__((ext_vector_type(4)));

union FragU { bf16x8 v; u16 u[8]; uint2 d2[2]; unsigned w[4]; uint4 q; };

__device__ __forceinline__ u16 f2bf(float f) {
  unsigned int x = __builtin_bit_cast(unsigned int, f);
  x += 0x7fffu + ((x >> 16) & 1u);   // round-to-nearest-even
  return (u16)(x >> 16);
}

__device__ __forceinline__ float fexp2(float x) {
  return __builtin_amdgcn_exp2f(x);   // raw v_exp_f32
}

// async global -> LDS, 16B per lane. dest = wave-uniform base + lane*16.
__device__ __forceinline__ void g2l(const void* g, void* l) {
  __builtin_amdgcn_global_load_lds(
      (const __attribute__((address_space(1))) unsigned int*)g,
      (__attribute__((address_space(3))) unsigned int*)l, 16, 0, 0);
}

#define MFMA16(a, b, c) __builtin_amdgcn_mfma_f32_16x16x32_bf16(a, b, c, 0, 0, 0)

// k-interleave within 32-group: p = ((m&15)>>2)*8 + ((m>>4)<<2) + (m&3)
#define KPERM(m) ((((m) & 15) >> 2) * 8 + (((m) >> 4) << 2) + ((m) & 3))

// ---------------------------------------------------------------------------
// prep v3: W -> WT bf16, k-interleaved. 192 blocks.
// ---------------------------------------------------------------------------
__global__ __launch_bounds__(256) void prep_kernel(
    const float* __restrict__ Wq, const float* __restrict__ Wk,
    const float* __restrict__ Wv, u16* __restrict__ WT)
{
  const int blk = blockIdx.x;
  const int z = blk >> 6, h = (blk >> 2) & 15, qtr = blk & 3;
  const float* src = ((z == 0) ? Wq : (z == 1) ? Wk : Wv) + (size_t)h * D_ * HD_;
  u16* dst = WT + (size_t)z * D_ * D_ + (size_t)h * HD_ * D_;
  const int tid = threadIdx.x;
  const int n = tid & 63, kh = tid >> 6;
  #pragma unroll
  for (int k32 = qtr * 2; k32 < qtr * 2 + 2; ++k32) {
    const int kbase = kh * 256 + k32 * 32;
    union { u16 u[32]; uint4 q[4]; } pk;
    #pragma unroll
    for (int m = 0; m < 32; ++m)
      pk.u[KPERM(m)] = f2bf(src[(size_t)(kbase + m) * HD_ + n]);
    #pragma unroll
    for (int j = 0; j < 4; ++j)
      *(uint4*)(dst + (size_t)n * D_ + kbase + j * 8) = pk.q[j];
  }
}

// ---------------------------------------------------------------------------
// proj v10 (r13): 64x128 tile, BK=64, A reg-staged from f32 X, B via
// global_load_lds from WT. Double-buffered 48 KB LDS. UNCHANGED.
// ---------------------------------------------------------------------------
__global__ __launch_bounds__(256) void proj_kernel(
    const float* __restrict__ Xq, const float* __restrict__ Xk, const float* __restrict__ Xv,
    const u16* __restrict__ WT,
    const float* __restrict__ bq, const float* __restrict__ bk, const float* __restrict__ bv,
    u16* __restrict__ qo, u16* __restrict__ ko, u16* __restrict__ vo)
{
  const int z = blockIdx.z;
  const int rowb = blockIdx.x;
  const int col  = blockIdx.y;
  const float* X  = (z == 0) ? Xq : (z == 1) ? Xk : Xv;
  const float* Bb = (z == 0) ? bq : (z == 1) ? bk : bv;
  u16* out = (z == 0) ? qo : (z == 1) ? ko : vo;
  const float scale = (z == 0) ? 0.125f * 1.44269504f : 1.0f;

  const int tid = threadIdx.x;
  const int l = tid & 63, w = tid >> 6;
  const int g = l >> 4, lr = l & 15;
  const int wm = w >> 1, wn = w & 1;

  __shared__ u16 As_[2][64 * 64];
  __shared__ u16 Bs_[2][128 * 64];

  const char* Wb = (const char*)(WT + (size_t)z * D_ * D_ + (size_t)col * 128 * D_);

  int bOff[4], bLds[4];
  #pragma unroll
  for (int i = 0; i < 4; ++i) {
    const int br = w * 32 + i * 8 + (l >> 3);
    bOff[i] = br * 2048 + (((l & 7) * 16) ^ ((br & 7) << 4));
    bLds[i] = (w * 4 + i) * 1024;
  }

  const int arow  = tid >> 2;
  const int aksub = (tid >> 1) & 1;
  const int ag0   = (tid & 1) * 2;
  const float* aSrc = X + (size_t)(rowb * 64 + arow) * D_ + aksub * 32 + ag0 * 4;
  const int asw = (arow & 7) << 4;
  const int aw0 = arow * 128 + ((aksub * 64 + ag0 * 16) ^ asw);
  const int aw1 = arow * 128 + ((aksub * 64 + (ag0 + 1) * 16) ^ asw);

  float4 a0, a1, a2, a3;

#define ALOAD(k0)                                                              \
  {                                                                            \
    const float* s = aSrc + (k0);                                              \
    a0 = *(const float4*)s;        a1 = *(const float4*)(s + 16);              \
    a2 = *(const float4*)(s + 4);  a3 = *(const float4*)(s + 20);              \
  }

#define AWRITE(buf)                                                            \
  {                                                                            \
    FragU t0, t1;                                                              \
    asm("v_cvt_pk_bf16_f32 %0, %1, %2" : "=v"(t0.w[0]) : "v"(a0.x), "v"(a0.y));\
    asm("v_cvt_pk_bf16_f32 %0, %1, %2" : "=v"(t0.w[1]) : "v"(a0.z), "v"(a0.w));\
    asm("v_cvt_pk_bf16_f32 %0, %1, %2" : "=v"(t0.w[2]) : "v"(a1.x), "v"(a1.y));\
    asm("v_cvt_pk_bf16_f32 %0, %1, %2" : "=v"(t0.w[3]) : "v"(a1.z), "v"(a1.w));\
    asm("v_cvt_pk_bf16_f32 %0, %1, %2" : "=v"(t1.w[0]) : "v"(a2.x), "v"(a2.y));\
    asm("v_cvt_pk_bf16_f32 %0, %1, %2" : "=v"(t1.w[1]) : "v"(a2.z), "v"(a2.w));\
    asm("v_cvt_pk_bf16_f32 %0, %1, %2" : "=v"(t1.w[2]) : "v"(a3.x), "v"(a3.y));\
    asm("v_cvt_pk_bf16_f32 %0, %1, %2" : "=v"(t1.w[3]) : "v"(a3.z), "v"(a3.w));\
    *(uint4*)((char*)As_[buf] + aw0) = t0.q;                                   \
    *(uint4*)((char*)As_[buf] + aw1) = t1.q;                                   \
  }

  ALOAD(0);
  AWRITE(0);
  #pragma unroll
  for (int i = 0; i < 4; ++i) g2l(Wb + bOff[i], (char*)Bs_[0] + bLds[i]);
  __syncthreads();

  const f32x4 zero = {0.f, 0.f, 0.f, 0.f};
  f32x4 acc[2][4];
  #pragma unroll
  for (int mt = 0; mt < 2; ++mt)
    #pragma unroll
    for (int nt = 0; nt < 4; ++nt) acc[mt][nt] = zero;

  for (int ks = 0; ks < 16; ++ks) {
    const int cur = ks & 1;
    if (ks < 15) {
      ALOAD((ks + 1) * 64);
      #pragma unroll
      for (int i = 0; i < 4; ++i)
        g2l(Wb + bOff[i] + (ks + 1) * 128, (char*)Bs_[cur ^ 1] + bLds[i]);
    }

    const char* Ac = (const char*)As_[cur];
    const char* Bc = (const char*)Bs_[cur];
    #pragma unroll
    for (int ksub = 0; ksub < 2; ++ksub) {
      FragU aF[2], bF[4];
      #pragma unroll
      for (int mt = 0; mt < 2; ++mt) {
        const int row = wm * 32 + mt * 16 + lr;
        aF[mt].v = *(const bf16x8*)(Ac + row * 128 +
                    ((ksub * 64 + g * 16) ^ ((row & 7) << 4)));
      }
      #pragma unroll
      for (int nt = 0; nt < 4; ++nt) {
        const int row = wn * 64 + nt * 16 + lr;
        bF[nt].v = *(const bf16x8*)(Bc + row * 128 +
                    ((ksub * 64 + g * 16) ^ ((row & 7) << 4)));
      }
      __builtin_amdgcn_s_setprio(1);
      #pragma unroll
      for (int mt = 0; mt < 2; ++mt)
        #pragma unroll
        for (int nt = 0; nt < 4; ++nt)
          acc[mt][nt] = MFMA16(aF[mt].v, bF[nt].v, acc[mt][nt]);
      __builtin_amdgcn_s_setprio(0);
    }

    if (ks < 15) AWRITE(cur ^ 1);
    __syncthreads();
  }

  #pragma unroll
  for (int nt = 0; nt < 4; ++nt) {
    const int ng = col * 128 + wn * 64 + nt * 16 + lr;
    const float bias = Bb[ng];
    const int h = ng >> 6, n = ng & 63;
    const int dperm = (n & 32) + ((n & 15) >> 2) * 8 + ((n & 16) >> 4) * 4 + (n & 3);
    #pragma unroll
    for (int mt = 0; mt < 2; ++mt) {
      const int R = rowb * 64 + wm * 32 + mt * 16 + g * 4;
      const int b = R >> 11, s0 = R & (S_ - 1);
      if (z < 2) {
        #pragma unroll
        for (int r = 0; r < 4; ++r)
          out[(((size_t)b * H_ + h) * S_ + s0 + r) * HD_ + dperm] =
              f2bf((acc[mt][nt][r] + bias) * scale);
      } else {
        const int a = (s0 >> 2) & 7;
        const int s0p = (s0 & ~31) + ((2 * (a & 3) + (a >> 2)) << 2);
        union { u16 u[4]; uint2 d; } pk;
        #pragma unroll
        for (int r = 0; r < 4; ++r) pk.u[r] = f2bf(acc[mt][nt][r] + bias);
        *(uint2*)(out + (((size_t)b * H_ + h) * HD_ + n) * S_ + s0p) = pk.d;
      }
    }
  }
#undef ALOAD
#undef AWRITE
}

// ---------------------------------------------------------------------------
// Flash attention v12: = v9 per-wave schedule, but 8 waves/block (512 thr,
// 256 q-rows/block, grid 256 = 1 block/CU). Halves staging loads, LDS
// ds_writes, and barrier events per q-row. Staging: 1 K + 1 V chunk/thread.
// ---------------------------------------------------------------------------
__global__ __launch_bounds__(512) void attn_kernel(
    const u16* __restrict__ q, const u16* __restrict__ k,
    const u16* __restrict__ vt, u16* __restrict__ attP, float* __restrict__ lrow)
{
  const int bid = blockIdx.x;
  const int xcd = bid & 7;
  const int t1 = bid >> 3;          // 0..31
  const int qt = t1 & 7;            // 8 q-tiles of 256
  const int bh = ((t1 >> 3) << 3) | xcd;

  const int tid = threadIdx.x;
  const int l = tid & 63, w = tid >> 6;   // w: 0..7
  const int g = l >> 4, lr = l & 15;
  const int qbase = qt * 256 + w * 32;

  #define BUFSZ (64 * 144)
  __shared__ __align__(16) char Ksm[2 * BUFSZ];
  __shared__ __align__(16) char Vsm[2 * BUFSZ];

  FragU qf[2][2];
  #pragma unroll
  for (int qg = 0; qg < 2; ++qg) {
    const char* qrow = (const char*)(q + ((size_t)bh * S_ + qbase + qg * 16 + lr) * HD_);
    qf[qg][0].v = *(const bf16x8*)(qrow + g * 16);
    qf[qg][1].v = *(const bf16x8*)(qrow + 64 + g * 16);
  }

  const char* kByte = (const char*)(k + (size_t)bh * S_ * HD_);
  const char* vByte = (const char*)(vt + (size_t)bh * HD_ * S_);

  // staging: ONE 16B K chunk + ONE 16B V chunk per thread (512 thr = 8 KB ea)
  const int off = tid * 16;
  const int rr = off >> 7, cc = off & 127;
  char* kD0 = Ksm + rr * 144 + cc;
  char* vD0 = Vsm + rr * 144 + cc;
  const char* kS0 = kByte + off;                       // + t0*128
  const char* vS0 = vByte + (size_t)rr * (S_ * 2) + cc;   // + t0*2

  uint4 kA = *(const uint4*)kS0;
  uint4 vA = *(const uint4*)vS0;
  *(uint4*)kD0 = kA;
  *(uint4*)vD0 = vA;
  __syncthreads();

  const f32x4 zero = {0.f, 0.f, 0.f, 0.f};
  f32x4 accO[2][4] = {{zero, zero, zero, zero}, {zero, zero, zero, zero}};
  float m_[2] = {-3e38f, -3e38f};
  float l_[2] = {0.f, 0.f};

  const char* kfb = Ksm + lr * 144 + g * 16;
  const char* vfb = Vsm + lr * 144 + g * 16;

  for (int t0 = 0; t0 < S_; t0 += 64) {
    const int cur = (t0 >> 6) & 1;
    const bool hasNext = (t0 + 64) < S_;
    if (hasNext) {
      kA = *(const uint4*)(kS0 + (t0 + 64) * 128);
      vA = *(const uint4*)(vS0 + (t0 + 64) * 2);
    }
    const char* kfbc = kfb + cur * BUFSZ;
    const char* vfbc = vfb + cur * BUFSZ;

    f32x4 sc[2][4] = {{zero, zero, zero, zero}, {zero, zero, zero, zero}};
    __builtin_amdgcn_s_setprio(1);
    #pragma unroll
    for (int ct = 0; ct < 4; ++ct) {
      FragU kf0, kf1;
      kf0.v = *(const bf16x8*)(kfbc + ct * 2304);
      kf1.v = *(const bf16x8*)(kfbc + ct * 2304 + 64);
      sc[0][ct] = MFMA16(kf0.v, qf[0][0].v, sc[0][ct]);
      sc[0][ct] = MFMA16(kf1.v, qf[0][1].v, sc[0][ct]);
      sc[1][ct] = MFMA16(kf0.v, qf[1][0].v, sc[1][ct]);
      sc[1][ct] = MFMA16(kf1.v, qf[1][1].v, sc[1][ct]);
    }
    __builtin_amdgcn_s_setprio(0);

    float lmax[2];
    #pragma unroll
    for (int qg = 0; qg < 2; ++qg) {
      float a0 = fmaxf(fmaxf(sc[qg][0][0], sc[qg][0][1]), fmaxf(sc[qg][0][2], sc[qg][0][3]));
      float a1 = fmaxf(fmaxf(sc[qg][1][0], sc[qg][1][1]), fmaxf(sc[qg][1][2], sc[qg][1][3]));
      float a2 = fmaxf(fmaxf(sc[qg][2][0], sc[qg][2][1]), fmaxf(sc[qg][2][2], sc[qg][2][3]));
      float a3 = fmaxf(fmaxf(sc[qg][3][0], sc[qg][3][1]), fmaxf(sc[qg][3][2], sc[qg][3][3]));
      lmax[qg] = fmaxf(fmaxf(a0, a1), fmaxf(a2, a3));
    }
    if (__any((lmax[0] - m_[0] > 8.f) || (lmax[1] - m_[1] > 8.f))) {
      #pragma unroll
      for (int qg = 0; qg < 2; ++qg) {
        float mm = lmax[qg];
        mm = fmaxf(mm, __shfl_xor(mm, 16));
        mm = fmaxf(mm, __shfl_xor(mm, 32));
        const float mn = fmaxf(m_[qg], mm);
        const float al = fexp2(m_[qg] - mn);
        m_[qg] = mn;
        l_[qg] *= al;
        float alr[4];
        #pragma unroll
        for (int r = 0; r < 4; ++r) alr[r] = __shfl(al, g * 4 + r);
        #pragma unroll
        for (int dt = 0; dt < 4; ++dt)
          #pragma unroll
          for (int r = 0; r < 4; ++r) accO[qg][dt][r] *= alr[r];
      }
    }

    FragU pf[2][2];
    #pragma unroll
    for (int qg = 0; qg < 2; ++qg) {
      #pragma unroll
      for (int ct = 0; ct < 4; ++ct)
        #pragma unroll
        for (int r = 0; r < 4; ++r)
          sc[qg][ct][r] = fexp2(sc[qg][ct][r] - m_[qg]);
      float s0 = (sc[qg][0][0] + sc[qg][0][1]) + (sc[qg][0][2] + sc[qg][0][3]);
      float s1 = (sc[qg][1][0] + sc[qg][1][1]) + (sc[qg][1][2] + sc[qg][1][3]);
      float s2 = (sc[qg][2][0] + sc[qg][2][1]) + (sc[qg][2][2] + sc[qg][2][3]);
      float s3 = (sc[qg][3][0] + sc[qg][3][1]) + (sc[qg][3][2] + sc[qg][3][3]);
      l_[qg] += (s0 + s1) + (s2 + s3);
      #pragma unroll
      for (int tc = 0; tc < 2; ++tc) {
        asm("v_cvt_pk_bf16_f32 %0, %1, %2" : "=v"(pf[qg][tc].w[0]) : "v"(sc[qg][2*tc][0]),   "v"(sc[qg][2*tc][1]));
        asm("v_cvt_pk_bf16_f32 %0, %1, %2" : "=v"(pf[qg][tc].w[1]) : "v"(sc[qg][2*tc][2]),   "v"(sc[qg][2*tc][3]));
        asm("v_cvt_pk_bf16_f32 %0, %1, %2" : "=v"(pf[qg][tc].w[2]) : "v"(sc[qg][2*tc+1][0]), "v"(sc[qg][2*tc+1][1]));
        asm("v_cvt_pk_bf16_f32 %0, %1, %2" : "=v"(pf[qg][tc].w[3]) : "v"(sc[qg][2*tc+1][2]), "v"(sc[qg][2*tc+1][3]));
      }
    }

    __builtin_amdgcn_s_setprio(1);
    #pragma unroll
    for (int dt = 0; dt < 4; ++dt) {
      FragU vf0, vf1;
      vf0.v = *(const bf16x8*)(vfbc + dt * 2304);
      vf1.v = *(const bf16x8*)(vfbc + dt * 2304 + 64);
      accO[0][dt] = MFMA16(pf[0][0].v, vf0.v, accO[0][dt]);
      accO[0][dt] = MFMA16(pf[0][1].v, vf1.v, accO[0][dt]);
      accO[1][dt] = MFMA16(pf[1][0].v, vf0.v, accO[1][dt]);
      accO[1][dt] = MFMA16(pf[1][1].v, vf1.v, accO[1][dt]);
    }
    __builtin_amdgcn_s_setprio(0);

    if (hasNext) {
      const int nb = (cur ^ 1) * BUFSZ;
      *(uint4*)(kD0 + nb) = kA;
      *(uint4*)(vD0 + nb) = vA;
    }
    __syncthreads();
  }

  const int b = bh >> 4, h = bh & (H_ - 1);
  u16* basep = attP + (size_t)b * S_ * D_;
  #pragma unroll
  for (int qg = 0; qg < 2; ++qg) {
    float lt = l_[qg];
    lt += __shfl_xor(lt, 16);
    lt += __shfl_xor(lt, 32);
    #pragma unroll
    for (int r = 0; r < 4; ++r) {
      const int s = qbase + qg * 16 + g * 4 + r;
      u16* op = basep + (size_t)s * D_ + h * HD_;
      #pragma unroll
      for (int dt = 0; dt < 4; ++dt) op[dt * 16 + lr] = f2bf(accO[qg][dt][r]);
    }
    if (g == 0)
      lrow[((size_t)b * H_ + h) * S_ + qbase + qg * 16 + lr] = lt;
  }
  #undef BUFSZ
}

// ---------------------------------------------------------------------------
// combine (divide by l) + LayerNorm, bf16 partial input.
// ---------------------------------------------------------------------------
__global__ __launch_bounds__(256) void combine_ln_kernel(
    const u16* __restrict__ attP, const float* __restrict__ lrow,
    const float* __restrict__ gamma, const float* __restrict__ beta,
    float* __restrict__ out)
{
  const int row = blockIdx.x;          // b*S + s
  const int b = row >> 11, s = row & (S_ - 1);
  const int tid = threadIdx.x;
  const int h = tid >> 4;

  const float inv = 1.0f / lrow[((size_t)b * H_ + h) * S_ + s];
  union { uint2 d; u16 u[4]; } raw;
  raw.d = ((const uint2*)(attP + (size_t)row * D_))[tid];
  float4 x;
  x.x = __builtin_bit_cast(float, (unsigned)raw.u[0] << 16) * inv;
  x.y = __builtin_bit_cast(float, (unsigned)raw.u[1] << 16) * inv;
  x.z = __builtin_bit_cast(float, (unsigned)raw.u[2] << 16) * inv;
  x.w = __builtin_bit_cast(float, (unsigned)raw.u[3] << 16) * inv;

  float sm = x.x + x.y + x.z + x.w;
  float sq = x.x * x.x + x.y * x.y + x.z * x.z + x.w * x.w;
  #pragma unroll
  for (int j = 1; j < 64; j <<= 1) { sm += __shfl_xor(sm, j); sq += __shfl_xor(sq, j); }
  __shared__ float ls[4], lq[4];
  const int w = tid >> 6;
  if ((tid & 63) == 0) { ls[w] = sm; lq[w] = sq; }
  __syncthreads();
  if (tid == 0) {
    ls[0] = ls[0] + ls[1] + ls[2] + ls[3];
    lq[0] = lq[0] + lq[1] + lq[2] + lq[3];
  }
  __syncthreads();
  const float mean = ls[0] * (1.f / D_);
  const float var  = lq[0] * (1.f / D_) - mean * mean;
  const float rs = rsqrtf(var + 1e-5f);
  const float4 gv = ((const float4*)gamma)[tid];
  const float4 bv = ((const float4*)beta)[tid];
  float4 o;
  o.x = (x.x - mean) * rs * gv.x + bv.x;
  o.y = (x.y - mean) * rs * gv.y + bv.y;
  o.z = (x.z - mean) * rs * gv.z + bv.z;
  o.w = (x.w - mean) * rs * gv.w + bv.w;
  ((float4*)(out + (size_t)row * D_))[tid] = o;
}

extern "C" void kernel_launch(void* const* d_in, const int* in_sizes, int n_in,
                              void* d_out, int out_size, void* d_ws, size_t ws_size,
                              hipStream_t stream) {
  const float* queries = (const float*)d_in[0];
  const float* keys    = (const float*)d_in[1];
  const float* values  = (const float*)d_in[2];
  const float* Wq = (const float*)d_in[3];
  const float* bq = (const float*)d_in[4];
  const float* Wk = (const float*)d_in[5];
  const float* bk = (const float*)d_in[6];
  const float* Wv = (const float*)d_in[7];
  const float* bv = (const float*)d_in[8];
  const float* gamma = (const float*)d_in[9];
  const float* beta  = (const float*)d_in[10];
  float* out = (float*)d_out;

  const size_t PER = (size_t)B_ * H_ * S_ * HD_;          // 4,194,304 elems
  u16* q_ws  = (u16*)d_ws;                                // 8 MB
  u16* k_ws  = q_ws + PER;                                // 8 MB
  u16* vt_ws = k_ws + PER;                                // 8 MB
  u16* WT   = vt_ws + PER;                                // 6 MB, dead after proj
  u16* attP = vt_ws + PER;                                // aliases WT (8 MB)
  const size_t NOUT = (size_t)B_ * S_ * D_;
  float* lrow = (float*)(attP + NOUT);

  prep_kernel<<<dim3(192), 256, 0, stream>>>(Wq, Wk, Wv, WT);
  proj_kernel<<<dim3(64, 8, 3), 256, 0, stream>>>(
      queries, keys, values, WT, bq, bk, bv, q_ws, k_ws, vt_ws);
  attn_kernel<<<dim3(256), 512, 0, stream>>>(q_ws, k_ws, vt_ws, attP, lrow);
  combine_ln_kernel<<<dim3(4096), 256, 0, stream>>>(attP, lrow, gamma, beta, out);
}

// Round 19
// 113.586 us; speedup vs baseline: 1.4023x; 1.0327x over previous
//
#include <hip/hip_runtime.h>

#define B_ 2
#define S_ 2048
#define D_ 1024
#define H_ 16
#define HD_ 64

typedef unsigned short u16;
typedef short bf16x8 __attribute__((ext_vector_type(8)));
typedef float f32x4 __attribute__((ext_vector_type(4)));

union FragU { bf16x8 v; u16 u[8]; uint2 d2[2]; unsigned w[4]; uint4 q; };

__device__ __forceinline__ u16 f2bf(float f) {
  unsigned int x = __builtin_bit_cast(unsigned int, f);
  x += 0x7fffu + ((x >> 16) & 1u);   // round-to-nearest-even
  return (u16)(x >> 16);
}

__device__ __forceinline__ float fexp2(float x) {
  return __builtin_amdgcn_exp2f(x);   // raw v_exp_f32
}

// async global -> LDS, 16B per lane. dest = wave-uniform base + lane*16.
__device__ __forceinline__ void g2l(const void* g, void* l) {
  __builtin_amdgcn_global_load_lds(
      (const __attribute__((address_space(1))) unsigned int*)g,
      (__attribute__((address_space(3))) unsigned int*)l, 16, 0, 0);
}

#define MFMA16(a, b, c) __builtin_amdgcn_mfma_f32_16x16x32_bf16(a, b, c, 0, 0, 0)

// k-interleave within 32-group: p = ((m&15)>>2)*8 + ((m>>4)<<2) + (m&3)
#define KPERM(m) ((((m) & 15) >> 2) * 8 + (((m) >> 4) << 2) + ((m) & 3))

// ---------------------------------------------------------------------------
// prep v3: W -> WT bf16, k-interleaved. 192 blocks.
// ---------------------------------------------------------------------------
__global__ __launch_bounds__(256) void prep_kernel(
    const float* __restrict__ Wq, const float* __restrict__ Wk,
    const float* __restrict__ Wv, u16* __restrict__ WT)
{
  const int blk = blockIdx.x;
  const int z = blk >> 6, h = (blk >> 2) & 15, qtr = blk & 3;
  const float* src = ((z == 0) ? Wq : (z == 1) ? Wk : Wv) + (size_t)h * D_ * HD_;
  u16* dst = WT + (size_t)z * D_ * D_ + (size_t)h * HD_ * D_;
  const int tid = threadIdx.x;
  const int n = tid & 63, kh = tid >> 6;
  #pragma unroll
  for (int k32 = qtr * 2; k32 < qtr * 2 + 2; ++k32) {
    const int kbase = kh * 256 + k32 * 32;
    union { u16 u[32]; uint4 q[4]; } pk;
    #pragma unroll
    for (int m = 0; m < 32; ++m)
      pk.u[KPERM(m)] = f2bf(src[(size_t)(kbase + m) * HD_ + n]);
    #pragma unroll
    for (int j = 0; j < 4; ++j)
      *(uint4*)(dst + (size_t)n * D_ + kbase + j * 8) = pk.q[j];
  }
}

// ---------------------------------------------------------------------------
// proj v12: 8 waves/block (512 thr), 128x128 tile, waves 4m x 2n so each
// wave's inner schedule is byte-identical to r13's v10 (32x64, acc[2][4]).
// Per k-step: 2x MFMA work per block, SAME barrier count, A-staging per
// thread unchanged, B-staging halved. 64 KB LDS -> 2 blocks/CU (16 waves).
// ---------------------------------------------------------------------------
__global__ __launch_bounds__(512) void proj_kernel(
    const float* __restrict__ Xq, const float* __restrict__ Xk, const float* __restrict__ Xv,
    const u16* __restrict__ WT,
    const float* __restrict__ bq, const float* __restrict__ bk, const float* __restrict__ bv,
    u16* __restrict__ qo, u16* __restrict__ ko, u16* __restrict__ vo)
{
  const int z = blockIdx.z;
  const int rowb = blockIdx.x;    // m-tile (32), fastest => XCD-local X panels
  const int col  = blockIdx.y;    // n-tile (8)
  const float* X  = (z == 0) ? Xq : (z == 1) ? Xk : Xv;
  const float* Bb = (z == 0) ? bq : (z == 1) ? bk : bv;
  u16* out = (z == 0) ? qo : (z == 1) ? ko : vo;
  const float scale = (z == 0) ? 0.125f * 1.44269504f : 1.0f;

  const int tid = threadIdx.x;
  const int l = tid & 63, w = tid >> 6;   // w: 0..7
  const int g = l >> 4, lr = l & 15;
  const int wm = w >> 1, wn = w & 1;      // 4m x 2n

  __shared__ u16 As_[2][128 * 64];   // 16 KB x2
  __shared__ u16 Bs_[2][128 * 64];   // 16 KB x2

  const char* Wb = (const char*)(WT + (size_t)z * D_ * D_ + (size_t)col * 128 * D_);

  // B staging: 2 g2l chunks per thread (1024 chunks / 512 threads)
  int bOff[2], bLds[2];
  #pragma unroll
  for (int i = 0; i < 2; ++i) {
    const int chunk = tid + i * 512;
    const int br = chunk >> 3, cb = (chunk & 7) * 16;
    bOff[i] = br * 2048 + (cb ^ ((br & 7) << 4));
    bLds[i] = (w * 64 + i * 512) * 16;   // wave-uniform base + lane*16
  }

  // A reg-staging (identical per-thread shape to r13): 128 rows over 512 thr
  const int arow  = tid >> 2;            // 0..127
  const int aksub = (tid >> 1) & 1;
  const int ag0   = (tid & 1) * 2;
  const float* aSrc = X + (size_t)(rowb * 128 + arow) * D_ + aksub * 32 + ag0 * 4;
  const int asw = (arow & 7) << 4;
  const int aw0 = arow * 128 + ((aksub * 64 + ag0 * 16) ^ asw);
  const int aw1 = arow * 128 + ((aksub * 64 + (ag0 + 1) * 16) ^ asw);

  float4 a0, a1, a2, a3;

#define ALOAD(k0)                                                              \
  {                                                                            \
    const float* s = aSrc + (k0);                                              \
    a0 = *(const float4*)s;        a1 = *(const float4*)(s + 16);              \
    a2 = *(const float4*)(s + 4);  a3 = *(const float4*)(s + 20);              \
  }

#define AWRITE(buf)                                                            \
  {                                                                            \
    FragU t0, t1;                                                              \
    asm("v_cvt_pk_bf16_f32 %0, %1, %2" : "=v"(t0.w[0]) : "v"(a0.x), "v"(a0.y));\
    asm("v_cvt_pk_bf16_f32 %0, %1, %2" : "=v"(t0.w[1]) : "v"(a0.z), "v"(a0.w));\
    asm("v_cvt_pk_bf16_f32 %0, %1, %2" : "=v"(t0.w[2]) : "v"(a1.x), "v"(a1.y));\
    asm("v_cvt_pk_bf16_f32 %0, %1, %2" : "=v"(t0.w[3]) : "v"(a1.z), "v"(a1.w));\
    asm("v_cvt_pk_bf16_f32 %0, %1, %2" : "=v"(t1.w[0]) : "v"(a2.x), "v"(a2.y));\
    asm("v_cvt_pk_bf16_f32 %0, %1, %2" : "=v"(t1.w[1]) : "v"(a2.z), "v"(a2.w));\
    asm("v_cvt_pk_bf16_f32 %0, %1, %2" : "=v"(t1.w[2]) : "v"(a3.x), "v"(a3.y));\
    asm("v_cvt_pk_bf16_f32 %0, %1, %2" : "=v"(t1.w[3]) : "v"(a3.z), "v"(a3.w));\
    *(uint4*)((char*)As_[buf] + aw0) = t0.q;                                   \
    *(uint4*)((char*)As_[buf] + aw1) = t1.q;                                   \
  }

  ALOAD(0);
  AWRITE(0);
  #pragma unroll
  for (int i = 0; i < 2; ++i) g2l(Wb + bOff[i], (char*)Bs_[0] + bLds[i]);
  __syncthreads();

  const f32x4 zero = {0.f, 0.f, 0.f, 0.f};
  f32x4 acc[2][4];
  #pragma unroll
  for (int mt = 0; mt < 2; ++mt)
    #pragma unroll
    for (int nt = 0; nt < 4; ++nt) acc[mt][nt] = zero;

  for (int ks = 0; ks < 16; ++ks) {
    const int cur = ks & 1;
    if (ks < 15) {
      ALOAD((ks + 1) * 64);
      #pragma unroll
      for (int i = 0; i < 2; ++i)
        g2l(Wb + bOff[i] + (ks + 1) * 128, (char*)Bs_[cur ^ 1] + bLds[i]);
    }

    const char* Ac = (const char*)As_[cur];
    const char* Bc = (const char*)Bs_[cur];
    #pragma unroll
    for (int ksub = 0; ksub < 2; ++ksub) {
      FragU aF[2], bF[4];
      #pragma unroll
      for (int mt = 0; mt < 2; ++mt) {
        const int row = wm * 32 + mt * 16 + lr;
        aF[mt].v = *(const bf16x8*)(Ac + row * 128 +
                    ((ksub * 64 + g * 16) ^ ((row & 7) << 4)));
      }
      #pragma unroll
      for (int nt = 0; nt < 4; ++nt) {
        const int row = wn * 64 + nt * 16 + lr;
        bF[nt].v = *(const bf16x8*)(Bc + row * 128 +
                    ((ksub * 64 + g * 16) ^ ((row & 7) << 4)));
      }
      __builtin_amdgcn_s_setprio(1);
      #pragma unroll
      for (int mt = 0; mt < 2; ++mt)
        #pragma unroll
        for (int nt = 0; nt < 4; ++nt)
          acc[mt][nt] = MFMA16(aF[mt].v, bF[nt].v, acc[mt][nt]);
      __builtin_amdgcn_s_setprio(0);
    }

    if (ks < 15) AWRITE(cur ^ 1);
    __syncthreads();
  }

  // epilogue: q/k -> d-interleaved [B,H,S,64]; v -> t-block-permuted [B,H,64,S]
  #pragma unroll
  for (int nt = 0; nt < 4; ++nt) {
    const int ng = col * 128 + wn * 64 + nt * 16 + lr;
    const float bias = Bb[ng];
    const int h = ng >> 6, n = ng & 63;
    const int dperm = (n & 32) + ((n & 15) >> 2) * 8 + ((n & 16) >> 4) * 4 + (n & 3);
    #pragma unroll
    for (int mt = 0; mt < 2; ++mt) {
      const int R = rowb * 128 + wm * 32 + mt * 16 + g * 4;
      const int b = R >> 11, s0 = R & (S_ - 1);
      if (z < 2) {
        #pragma unroll
        for (int r = 0; r < 4; ++r)
          out[(((size_t)b * H_ + h) * S_ + s0 + r) * HD_ + dperm] =
              f2bf((acc[mt][nt][r] + bias) * scale);
      } else {
        const int a = (s0 >> 2) & 7;
        const int s0p = (s0 & ~31) + ((2 * (a & 3) + (a >> 2)) << 2);
        union { u16 u[4]; uint2 d; } pk;
        #pragma unroll
        for (int r = 0; r < 4; ++r) pk.u[r] = f2bf(acc[mt][nt][r] + bias);
        *(uint2*)(out + (((size_t)b * H_ + h) * HD_ + n) * S_ + s0p) = pk.d;
      }
    }
  }
#undef ALOAD
#undef AWRITE
}

// ---------------------------------------------------------------------------
// Flash attention v12 (r18, unchanged): 8 waves/block, 256 q-rows/block,
// grid 256; KVBLK=64 dbuf, one barrier/iter, per-lane l, defer-max, v_exp.
// ---------------------------------------------------------------------------
__global__ __launch_bounds__(512) void attn_kernel(
    const u16* __restrict__ q, const u16* __restrict__ k,
    const u16* __restrict__ vt, u16* __restrict__ attP, float* __restrict__ lrow)
{
  const int bid = blockIdx.x;
  const int xcd = bid & 7;
  const int t1 = bid >> 3;
  const int qt = t1 & 7;
  const int bh = ((t1 >> 3) << 3) | xcd;

  const int tid = threadIdx.x;
  const int l = tid & 63, w = tid >> 6;
  const int g = l >> 4, lr = l & 15;
  const int qbase = qt * 256 + w * 32;

  #define BUFSZ (64 * 144)
  __shared__ __align__(16) char Ksm[2 * BUFSZ];
  __shared__ __align__(16) char Vsm[2 * BUFSZ];

  FragU qf[2][2];
  #pragma unroll
  for (int qg = 0; qg < 2; ++qg) {
    const char* qrow = (const char*)(q + ((size_t)bh * S_ + qbase + qg * 16 + lr) * HD_);
    qf[qg][0].v = *(const bf16x8*)(qrow + g * 16);
    qf[qg][1].v = *(const bf16x8*)(qrow + 64 + g * 16);
  }

  const char* kByte = (const char*)(k + (size_t)bh * S_ * HD_);
  const char* vByte = (const char*)(vt + (size_t)bh * HD_ * S_);

  const int off = tid * 16;
  const int rr = off >> 7, cc = off & 127;
  char* kD0 = Ksm + rr * 144 + cc;
  char* vD0 = Vsm + rr * 144 + cc;
  const char* kS0 = kByte + off;
  const char* vS0 = vByte + (size_t)rr * (S_ * 2) + cc;

  uint4 kA = *(const uint4*)kS0;
  uint4 vA = *(const uint4*)vS0;
  *(uint4*)kD0 = kA;
  *(uint4*)vD0 = vA;
  __syncthreads();

  const f32x4 zero = {0.f, 0.f, 0.f, 0.f};
  f32x4 accO[2][4] = {{zero, zero, zero, zero}, {zero, zero, zero, zero}};
  float m_[2] = {-3e38f, -3e38f};
  float l_[2] = {0.f, 0.f};

  const char* kfb = Ksm + lr * 144 + g * 16;
  const char* vfb = Vsm + lr * 144 + g * 16;

  for (int t0 = 0; t0 < S_; t0 += 64) {
    const int cur = (t0 >> 6) & 1;
    const bool hasNext = (t0 + 64) < S_;
    if (hasNext) {
      kA = *(const uint4*)(kS0 + (t0 + 64) * 128);
      vA = *(const uint4*)(vS0 + (t0 + 64) * 2);
    }
    const char* kfbc = kfb + cur * BUFSZ;
    const char* vfbc = vfb + cur * BUFSZ;

    f32x4 sc[2][4] = {{zero, zero, zero, zero}, {zero, zero, zero, zero}};
    __builtin_amdgcn_s_setprio(1);
    #pragma unroll
    for (int ct = 0; ct < 4; ++ct) {
      FragU kf0, kf1;
      kf0.v = *(const bf16x8*)(kfbc + ct * 2304);
      kf1.v = *(const bf16x8*)(kfbc + ct * 2304 + 64);
      sc[0][ct] = MFMA16(kf0.v, qf[0][0].v, sc[0][ct]);
      sc[0][ct] = MFMA16(kf1.v, qf[0][1].v, sc[0][ct]);
      sc[1][ct] = MFMA16(kf0.v, qf[1][0].v, sc[1][ct]);
      sc[1][ct] = MFMA16(kf1.v, qf[1][1].v, sc[1][ct]);
    }
    __builtin_amdgcn_s_setprio(0);

    float lmax[2];
    #pragma unroll
    for (int qg = 0; qg < 2; ++qg) {
      float a0 = fmaxf(fmaxf(sc[qg][0][0], sc[qg][0][1]), fmaxf(sc[qg][0][2], sc[qg][0][3]));
      float a1 = fmaxf(fmaxf(sc[qg][1][0], sc[qg][1][1]), fmaxf(sc[qg][1][2], sc[qg][1][3]));
      float a2 = fmaxf(fmaxf(sc[qg][2][0], sc[qg][2][1]), fmaxf(sc[qg][2][2], sc[qg][2][3]));
      float a3 = fmaxf(fmaxf(sc[qg][3][0], sc[qg][3][1]), fmaxf(sc[qg][3][2], sc[qg][3][3]));
      lmax[qg] = fmaxf(fmaxf(a0, a1), fmaxf(a2, a3));
    }
    if (__any((lmax[0] - m_[0] > 8.f) || (lmax[1] - m_[1] > 8.f))) {
      #pragma unroll
      for (int qg = 0; qg < 2; ++qg) {
        float mm = lmax[qg];
        mm = fmaxf(mm, __shfl_xor(mm, 16));
        mm = fmaxf(mm, __shfl_xor(mm, 32));
        const float mn = fmaxf(m_[qg], mm);
        const float al = fexp2(m_[qg] - mn);
        m_[qg] = mn;
        l_[qg] *= al;
        float alr[4];
        #pragma unroll
        for (int r = 0; r < 4; ++r) alr[r] = __shfl(al, g * 4 + r);
        #pragma unroll
        for (int dt = 0; dt < 4; ++dt)
          #pragma unroll
          for (int r = 0; r < 4; ++r) accO[qg][dt][r] *= alr[r];
      }
    }

    FragU pf[2][2];
    #pragma unroll
    for (int qg = 0; qg < 2; ++qg) {
      #pragma unroll
      for (int ct = 0; ct < 4; ++ct)
        #pragma unroll
        for (int r = 0; r < 4; ++r)
          sc[qg][ct][r] = fexp2(sc[qg][ct][r] - m_[qg]);
      float s0 = (sc[qg][0][0] + sc[qg][0][1]) + (sc[qg][0][2] + sc[qg][0][3]);
      float s1 = (sc[qg][1][0] + sc[qg][1][1]) + (sc[qg][1][2] + sc[qg][1][3]);
      float s2 = (sc[qg][2][0] + sc[qg][2][1]) + (sc[qg][2][2] + sc[qg][2][3]);
      float s3 = (sc[qg][3][0] + sc[qg][3][1]) + (sc[qg][3][2] + sc[qg][3][3]);
      l_[qg] += (s0 + s1) + (s2 + s3);
      #pragma unroll
      for (int tc = 0; tc < 2; ++tc) {
        asm("v_cvt_pk_bf16_f32 %0, %1, %2" : "=v"(pf[qg][tc].w[0]) : "v"(sc[qg][2*tc][0]),   "v"(sc[qg][2*tc][1]));
        asm("v_cvt_pk_bf16_f32 %0, %1, %2" : "=v"(pf[qg][tc].w[1]) : "v"(sc[qg][2*tc][2]),   "v"(sc[qg][2*tc][3]));
        asm("v_cvt_pk_bf16_f32 %0, %1, %2" : "=v"(pf[qg][tc].w[2]) : "v"(sc[qg][2*tc+1][0]), "v"(sc[qg][2*tc+1][1]));
        asm("v_cvt_pk_bf16_f32 %0, %1, %2" : "=v"(pf[qg][tc].w[3]) : "v"(sc[qg][2*tc+1][2]), "v"(sc[qg][2*tc+1][3]));
      }
    }

    __builtin_amdgcn_s_setprio(1);
    #pragma unroll
    for (int dt = 0; dt < 4; ++dt) {
      FragU vf0, vf1;
      vf0.v = *(const bf16x8*)(vfbc + dt * 2304);
      vf1.v = *(const bf16x8*)(vfbc + dt * 2304 + 64);
      accO[0][dt] = MFMA16(pf[0][0].v, vf0.v, accO[0][dt]);
      accO[0][dt] = MFMA16(pf[0][1].v, vf1.v, accO[0][dt]);
      accO[1][dt] = MFMA16(pf[1][0].v, vf0.v, accO[1][dt]);
      accO[1][dt] = MFMA16(pf[1][1].v, vf1.v, accO[1][dt]);
    }
    __builtin_amdgcn_s_setprio(0);

    if (hasNext) {
      const int nb = (cur ^ 1) * BUFSZ;
      *(uint4*)(kD0 + nb) = kA;
      *(uint4*)(vD0 + nb) = vA;
    }
    __syncthreads();
  }

  const int b = bh >> 4, h = bh & (H_ - 1);
  u16* basep = attP + (size_t)b * S_ * D_;
  #pragma unroll
  for (int qg = 0; qg < 2; ++qg) {
    float lt = l_[qg];
    lt += __shfl_xor(lt, 16);
    lt += __shfl_xor(lt, 32);
    #pragma unroll
    for (int r = 0; r < 4; ++r) {
      const int s = qbase + qg * 16 + g * 4 + r;
      u16* op = basep + (size_t)s * D_ + h * HD_;
      #pragma unroll
      for (int dt = 0; dt < 4; ++dt) op[dt * 16 + lr] = f2bf(accO[qg][dt][r]);
    }
    if (g == 0)
      lrow[((size_t)b * H_ + h) * S_ + qbase + qg * 16 + lr] = lt;
  }
  #undef BUFSZ
}

// ---------------------------------------------------------------------------
// combine (divide by l) + LayerNorm, bf16 partial input.
// ---------------------------------------------------------------------------
__global__ __launch_bounds__(256) void combine_ln_kernel(
    const u16* __restrict__ attP, const float* __restrict__ lrow,
    const float* __restrict__ gamma, const float* __restrict__ beta,
    float* __restrict__ out)
{
  const int row = blockIdx.x;          // b*S + s
  const int b = row >> 11, s = row & (S_ - 1);
  const int tid = threadIdx.x;
  const int h = tid >> 4;

  const float inv = 1.0f / lrow[((size_t)b * H_ + h) * S_ + s];
  union { uint2 d; u16 u[4]; } raw;
  raw.d = ((const uint2*)(attP + (size_t)row * D_))[tid];
  float4 x;
  x.x = __builtin_bit_cast(float, (unsigned)raw.u[0] << 16) * inv;
  x.y = __builtin_bit_cast(float, (unsigned)raw.u[1] << 16) * inv;
  x.z = __builtin_bit_cast(float, (unsigned)raw.u[2] << 16) * inv;
  x.w = __builtin_bit_cast(float, (unsigned)raw.u[3] << 16) * inv;

  float sm = x.x + x.y + x.z + x.w;
  float sq = x.x * x.x + x.y * x.y + x.z * x.z + x.w * x.w;
  #pragma unroll
  for (int j = 1; j < 64; j <<= 1) { sm += __shfl_xor(sm, j); sq += __shfl_xor(sq, j); }
  __shared__ float ls[4], lq[4];
  const int w = tid >> 6;
  if ((tid & 63) == 0) { ls[w] = sm; lq[w] = sq; }
  __syncthreads();
  if (tid == 0) {
    ls[0] = ls[0] + ls[1] + ls[2] + ls[3];
    lq[0] = lq[0] + lq[1] + lq[2] + lq[3];
  }
  __syncthreads();
  const float mean = ls[0] * (1.f / D_);
  const float var  = lq[0] * (1.f / D_) - mean * mean;
  const float rs = rsqrtf(var + 1e-5f);
  const float4 gv = ((const float4*)gamma)[tid];
  const float4 bv = ((const float4*)beta)[tid];
  float4 o;
  o.x = (x.x - mean) * rs * gv.x + bv.x;
  o.y = (x.y - mean) * rs * gv.y + bv.y;
  o.z = (x.z - mean) * rs * gv.z + bv.z;
  o.w = (x.w - mean) * rs * gv.w + bv.w;
  ((float4*)(out + (size_t)row * D_))[tid] = o;
}

extern "C" void kernel_launch(void* const* d_in, const int* in_sizes, int n_in,
                              void* d_out, int out_size, void* d_ws, size_t ws_size,
                              hipStream_t stream) {
  const float* queries = (const float*)d_in[0];
  const float* keys    = (const float*)d_in[1];
  const float* values  = (const float*)d_in[2];
  const float* Wq = (const float*)d_in[3];
  const float* bq = (const float*)d_in[4];
  const float* Wk = (const float*)d_in[5];
  const float* bk = (const float*)d_in[6];
  const float* Wv = (const float*)d_in[7];
  const float* bv = (const float*)d_in[8];
  const float* gamma = (const float*)d_in[9];
  const float* beta  = (const float*)d_in[10];
  float* out = (float*)d_out;

  const size_t PER = (size_t)B_ * H_ * S_ * HD_;          // 4,194,304 elems
  u16* q_ws  = (u16*)d_ws;                                // 8 MB
  u16* k_ws  = q_ws + PER;                                // 8 MB
  u16* vt_ws = k_ws + PER;                                // 8 MB
  u16* WT   = vt_ws + PER;                                // 6 MB, dead after proj
  u16* attP = vt_ws + PER;                                // aliases WT (8 MB)
  const size_t NOUT = (size_t)B_ * S_ * D_;
  float* lrow = (float*)(attP + NOUT);

  prep_kernel<<<dim3(192), 256, 0, stream>>>(Wq, Wk, Wv, WT);
  proj_kernel<<<dim3(32, 8, 3), 512, 0, stream>>>(
      queries, keys, values, WT, bq, bk, bv, q_ws, k_ws, vt_ws);
  attn_kernel<<<dim3(256), 512, 0, stream>>>(q_ws, k_ws, vt_ws, attP, lrow);
  combine_ln_kernel<<<dim3(4096), 256, 0, stream>>>(attP, lrow, gamma, beta, out);
}

// Round 20
// 113.575 us; speedup vs baseline: 1.4024x; 1.0001x over previous
//
#include <hip/hip_runtime.h>

#define B_ 2
#define S_ 2048
#define D_ 1024
#define H_ 16
#define HD_ 64

typedef unsigned short u16;
typedef short bf16x8 __attribute__((ext_vector_type(8)));
typedef float f32x4 __attribute__((ext_vector_type(4)));

union FragU { bf16x8 v; u16 u[8]; uint2 d2[2]; unsigned w[4]; uint4 q; };

__device__ __forceinline__ u16 f2bf(float f) {
  unsigned int x = __builtin_bit_cast(unsigned int, f);
  x += 0x7fffu + ((x >> 16) & 1u);   // round-to-nearest-even
  return (u16)(x >> 16);
}

__device__ __forceinline__ float fexp2(float x) {
  return __builtin_amdgcn_exp2f(x);   // raw v_exp_f32
}

// async global -> LDS, 16B per lane. dest = wave-uniform base + lane*16.
__device__ __forceinline__ void g2l(const void* g, void* l) {
  __builtin_amdgcn_global_load_lds(
      (const __attribute__((address_space(1))) unsigned int*)g,
      (__attribute__((address_space(3))) unsigned int*)l, 16, 0, 0);
}

#define MFMA16(a, b, c) __builtin_amdgcn_mfma_f32_16x16x32_bf16(a, b, c, 0, 0, 0)

// k-interleave within 32-group: p = ((m&15)>>2)*8 + ((m>>4)<<2) + (m&3)
#define KPERM(m) ((((m) & 15) >> 2) * 8 + (((m) >> 4) << 2) + ((m) & 3))

// ---------------------------------------------------------------------------
// prep v3: W -> WT bf16, k-interleaved. 192 blocks.
// ---------------------------------------------------------------------------
__global__ __launch_bounds__(256) void prep_kernel(
    const float* __restrict__ Wq, const float* __restrict__ Wk,
    const float* __restrict__ Wv, u16* __restrict__ WT)
{
  const int blk = blockIdx.x;
  const int z = blk >> 6, h = (blk >> 2) & 15, qtr = blk & 3;
  const float* src = ((z == 0) ? Wq : (z == 1) ? Wk : Wv) + (size_t)h * D_ * HD_;
  u16* dst = WT + (size_t)z * D_ * D_ + (size_t)h * HD_ * D_;
  const int tid = threadIdx.x;
  const int n = tid & 63, kh = tid >> 6;
  #pragma unroll
  for (int k32 = qtr * 2; k32 < qtr * 2 + 2; ++k32) {
    const int kbase = kh * 256 + k32 * 32;
    union { u16 u[32]; uint4 q[4]; } pk;
    #pragma unroll
    for (int m = 0; m < 32; ++m)
      pk.u[KPERM(m)] = f2bf(src[(size_t)(kbase + m) * HD_ + n]);
    #pragma unroll
    for (int j = 0; j < 4; ++j)
      *(uint4*)(dst + (size_t)n * D_ + kbase + j * 8) = pk.q[j];
  }
}

// ---------------------------------------------------------------------------
// proj v13: = v12 (8 waves, 128x128, reg-staged A + g2l B) but with RAW
// s_barrier + counted vmcnt (T4): A prefetch depth 2 (two named reg sets),
// issue order pinned [B g2l, then A loads], pre-barrier wait vmcnt(4) keeps
// the 4 A-loads for step+2 in flight ACROSS the barrier. lgkmcnt(0)
// publishes ds_writes. Tail steps drain to 0.
// ---------------------------------------------------------------------------
__global__ __launch_bounds__(512) void proj_kernel(
    const float* __restrict__ Xq, const float* __restrict__ Xk, const float* __restrict__ Xv,
    const u16* __restrict__ WT,
    const float* __restrict__ bq, const float* __restrict__ bk, const float* __restrict__ bv,
    u16* __restrict__ qo, u16* __restrict__ ko, u16* __restrict__ vo)
{
  const int z = blockIdx.z;
  const int rowb = blockIdx.x;    // m-tile (32), fastest => XCD-local X panels
  const int col  = blockIdx.y;    // n-tile (8)
  const float* X  = (z == 0) ? Xq : (z == 1) ? Xk : Xv;
  const float* Bb = (z == 0) ? bq : (z == 1) ? bk : bv;
  u16* out = (z == 0) ? qo : (z == 1) ? ko : vo;
  const float scale = (z == 0) ? 0.125f * 1.44269504f : 1.0f;

  const int tid = threadIdx.x;
  const int l = tid & 63, w = tid >> 6;
  const int g = l >> 4, lr = l & 15;
  const int wm = w >> 1, wn = w & 1;

  __shared__ u16 As_[2][128 * 64];   // 16 KB x2
  __shared__ u16 Bs_[2][128 * 64];   // 16 KB x2

  const char* Wb = (const char*)(WT + (size_t)z * D_ * D_ + (size_t)col * 128 * D_);

  // B staging: 2 g2l chunks per thread
  int bOff[2], bLds[2];
  #pragma unroll
  for (int i = 0; i < 2; ++i) {
    const int chunk = tid + i * 512;
    const int br = chunk >> 3, cb = (chunk & 7) * 16;
    bOff[i] = br * 2048 + (cb ^ ((br & 7) << 4));
    bLds[i] = (w * 64 + i * 512) * 16;
  }

  // A reg-staging geometry (same as v12)
  const int arow  = tid >> 2;
  const int aksub = (tid >> 1) & 1;
  const int ag0   = (tid & 1) * 2;
  const float* aSrc = X + (size_t)(rowb * 128 + arow) * D_ + aksub * 32 + ag0 * 4;
  const int asw = (arow & 7) << 4;
  const int aw0 = arow * 128 + ((aksub * 64 + ag0 * 16) ^ asw);
  const int aw1 = arow * 128 + ((aksub * 64 + (ag0 + 1) * 16) ^ asw);

  // two named A register sets (static indexing; depth-2 prefetch)
  float4 xA0, xA1, xA2, xA3;
  float4 xB0, xB1, xB2, xB3;

#define BSTG(buf, k0)                                                          \
  {                                                                            \
    g2l(Wb + bOff[0] + (k0) * 2, (char*)Bs_[buf] + bLds[0]);                   \
    g2l(Wb + bOff[1] + (k0) * 2, (char*)Bs_[buf] + bLds[1]);                   \
    __builtin_amdgcn_sched_barrier(0); /* pin: B g2l issued before A loads */  \
  }

#define ALOADS(p0, p1, p2, p3, k0)                                             \
  {                                                                            \
    const float* s = aSrc + (k0);                                              \
    p0 = *(const float4*)s;        p1 = *(const float4*)(s + 16);              \
    p2 = *(const float4*)(s + 4);  p3 = *(const float4*)(s + 20);              \
  }

#define AWR(p0, p1, p2, p3, buf)                                               \
  {                                                                            \
    FragU t0, t1;                                                              \
    asm("v_cvt_pk_bf16_f32 %0, %1, %2" : "=v"(t0.w[0]) : "v"(p0.x), "v"(p0.y));\
    asm("v_cvt_pk_bf16_f32 %0, %1, %2" : "=v"(t0.w[1]) : "v"(p0.z), "v"(p0.w));\
    asm("v_cvt_pk_bf16_f32 %0, %1, %2" : "=v"(t0.w[2]) : "v"(p1.x), "v"(p1.y));\
    asm("v_cvt_pk_bf16_f32 %0, %1, %2" : "=v"(t0.w[3]) : "v"(p1.z), "v"(p1.w));\
    asm("v_cvt_pk_bf16_f32 %0, %1, %2" : "=v"(t1.w[0]) : "v"(p2.x), "v"(p2.y));\
    asm("v_cvt_pk_bf16_f32 %0, %1, %2" : "=v"(t1.w[1]) : "v"(p2.z), "v"(p2.w));\
    asm("v_cvt_pk_bf16_f32 %0, %1, %2" : "=v"(t1.w[2]) : "v"(p3.x), "v"(p3.y));\
    asm("v_cvt_pk_bf16_f32 %0, %1, %2" : "=v"(t1.w[3]) : "v"(p3.z), "v"(p3.w));\
    *(uint4*)((char*)As_[buf] + aw0) = t0.q;                                   \
    *(uint4*)((char*)As_[buf] + aw1) = t1.q;                                   \
  }

#define COMPUTE(buf)                                                           \
  {                                                                            \
    const char* Ac = (const char*)As_[buf];                                    \
    const char* Bc = (const char*)Bs_[buf];                                    \
    _Pragma("unroll")                                                          \
    for (int ksub = 0; ksub < 2; ++ksub) {                                     \
      FragU aF[2], bF[4];                                                      \
      _Pragma("unroll")                                                        \
      for (int mt = 0; mt < 2; ++mt) {                                         \
        const int row = wm * 32 + mt * 16 + lr;                                \
        aF[mt].v = *(const bf16x8*)(Ac + row * 128 +                           \
                    ((ksub * 64 + g * 16) ^ ((row & 7) << 4)));                \
      }                                                                        \
      _Pragma("unroll")                                                        \
      for (int nt = 0; nt < 4; ++nt) {                                         \
        const int row = wn * 64 + nt * 16 + lr;                                \
        bF[nt].v = *(const bf16x8*)(Bc + row * 128 +                           \
                    ((ksub * 64 + g * 16) ^ ((row & 7) << 4)));                \
      }                                                                        \
      __builtin_amdgcn_s_setprio(1);                                           \
      _Pragma("unroll")                                                        \
      for (int mt = 0; mt < 2; ++mt)                                           \
        _Pragma("unroll")                                                      \
        for (int nt = 0; nt < 4; ++nt)                                         \
          acc[mt][nt] = MFMA16(aF[mt].v, bF[nt].v, acc[mt][nt]);               \
      __builtin_amdgcn_s_setprio(0);                                           \
    }                                                                          \
  }

#define SYNC4()                                                                \
  asm volatile("s_waitcnt vmcnt(4) lgkmcnt(0)" ::: "memory");                  \
  __builtin_amdgcn_s_barrier();                                                \
  __builtin_amdgcn_sched_barrier(0);

#define SYNC0()                                                                \
  asm volatile("s_waitcnt vmcnt(0) lgkmcnt(0)" ::: "memory");                  \
  __builtin_amdgcn_s_barrier();                                                \
  __builtin_amdgcn_sched_barrier(0);

  const f32x4 zero = {0.f, 0.f, 0.f, 0.f};
  f32x4 acc[2][4];
  #pragma unroll
  for (int mt = 0; mt < 2; ++mt)
    #pragma unroll
    for (int nt = 0; nt < 4; ++nt) acc[mt][nt] = zero;

  // prologue: A(0)->buf0; issue B(0); load A(1) into set-B regs
  ALOADS(xA0, xA1, xA2, xA3, 0);
  AWR(xA0, xA1, xA2, xA3, 0);
  BSTG(0, 0);
  ALOADS(xB0, xB1, xB2, xB3, 64);
  SYNC4();   // drains B(0) (issued before A(1)); A(1) stays in flight

  // steady: steps 0..13 (7 iterations x 2 steps)
  for (int i = 0; i < 7; ++i) {
    const int e = 2 * i;
    // even step e: compute buf0; stage B(e+1)->buf1; load A(e+2); write A(e+1)->buf1
    BSTG(1, (e + 1) * 64);
    ALOADS(xA0, xA1, xA2, xA3, (e + 2) * 64);
    COMPUTE(0);
    AWR(xB0, xB1, xB2, xB3, 1);
    SYNC4();
    // odd step e+1: compute buf1; stage B(e+2)->buf0; load A(e+3); write A(e+2)->buf0
    BSTG(0, (e + 2) * 64);
    ALOADS(xB0, xB1, xB2, xB3, (e + 3) * 64);
    COMPUTE(1);
    AWR(xA0, xA1, xA2, xA3, 0);
    SYNC4();
  }

  // step 14: stage B(15)->buf1; compute buf0; write A(15)->buf1; full drain
  BSTG(1, 15 * 64);
  COMPUTE(0);
  AWR(xB0, xB1, xB2, xB3, 1);
  SYNC0();
  // step 15: compute buf1
  COMPUTE(1);

  // epilogue: q/k -> d-interleaved [B,H,S,64]; v -> t-block-permuted [B,H,64,S]
  #pragma unroll
  for (int nt = 0; nt < 4; ++nt) {
    const int ng = col * 128 + wn * 64 + nt * 16 + lr;
    const float bias = Bb[ng];
    const int h = ng >> 6, n = ng & 63;
    const int dperm = (n & 32) + ((n & 15) >> 2) * 8 + ((n & 16) >> 4) * 4 + (n & 3);
    #pragma unroll
    for (int mt = 0; mt < 2; ++mt) {
      const int R = rowb * 128 + wm * 32 + mt * 16 + g * 4;
      const int b = R >> 11, s0 = R & (S_ - 1);
      if (z < 2) {
        #pragma unroll
        for (int r = 0; r < 4; ++r)
          out[(((size_t)b * H_ + h) * S_ + s0 + r) * HD_ + dperm] =
              f2bf((acc[mt][nt][r] + bias) * scale);
      } else {
        const int a = (s0 >> 2) & 7;
        const int s0p = (s0 & ~31) + ((2 * (a & 3) + (a >> 2)) << 2);
        union { u16 u[4]; uint2 d; } pk;
        #pragma unroll
        for (int r = 0; r < 4; ++r) pk.u[r] = f2bf(acc[mt][nt][r] + bias);
        *(uint2*)(out + (((size_t)b * H_ + h) * HD_ + n) * S_ + s0p) = pk.d;
      }
    }
  }
#undef BSTG
#undef ALOADS
#undef AWR
#undef COMPUTE
#undef SYNC4
#undef SYNC0
}

// ---------------------------------------------------------------------------
// Flash attention v12 (r18/r19, unchanged): 8 waves/block, 256 q-rows/block,
// grid 256; KVBLK=64 dbuf, one barrier/iter, per-lane l, defer-max, v_exp.
// ---------------------------------------------------------------------------
__global__ __launch_bounds__(512) void attn_kernel(
    const u16* __restrict__ q, const u16* __restrict__ k,
    const u16* __restrict__ vt, u16* __restrict__ attP, float* __restrict__ lrow)
{
  const int bid = blockIdx.x;
  const int xcd = bid & 7;
  const int t1 = bid >> 3;
  const int qt = t1 & 7;
  const int bh = ((t1 >> 3) << 3) | xcd;

  const int tid = threadIdx.x;
  const int l = tid & 63, w = tid >> 6;
  const int g = l >> 4, lr = l & 15;
  const int qbase = qt * 256 + w * 32;

  #define BUFSZ (64 * 144)
  __shared__ __align__(16) char Ksm[2 * BUFSZ];
  __shared__ __align__(16) char Vsm[2 * BUFSZ];

  FragU qf[2][2];
  #pragma unroll
  for (int qg = 0; qg < 2; ++qg) {
    const char* qrow = (const char*)(q + ((size_t)bh * S_ + qbase + qg * 16 + lr) * HD_);
    qf[qg][0].v = *(const bf16x8*)(qrow + g * 16);
    qf[qg][1].v = *(const bf16x8*)(qrow + 64 + g * 16);
  }

  const char* kByte = (const char*)(k + (size_t)bh * S_ * HD_);
  const char* vByte = (const char*)(vt + (size_t)bh * HD_ * S_);

  const int off = tid * 16;
  const int rr = off >> 7, cc = off & 127;
  char* kD0 = Ksm + rr * 144 + cc;
  char* vD0 = Vsm + rr * 144 + cc;
  const char* kS0 = kByte + off;
  const char* vS0 = vByte + (size_t)rr * (S_ * 2) + cc;

  uint4 kA = *(const uint4*)kS0;
  uint4 vA = *(const uint4*)vS0;
  *(uint4*)kD0 = kA;
  *(uint4*)vD0 = vA;
  __syncthreads();

  const f32x4 zero = {0.f, 0.f, 0.f, 0.f};
  f32x4 accO[2][4] = {{zero, zero, zero, zero}, {zero, zero, zero, zero}};
  float m_[2] = {-3e38f, -3e38f};
  float l_[2] = {0.f, 0.f};

  const char* kfb = Ksm + lr * 144 + g * 16;
  const char* vfb = Vsm + lr * 144 + g * 16;

  for (int t0 = 0; t0 < S_; t0 += 64) {
    const int cur = (t0 >> 6) & 1;
    const bool hasNext = (t0 + 64) < S_;
    if (hasNext) {
      kA = *(const uint4*)(kS0 + (t0 + 64) * 128);
      vA = *(const uint4*)(vS0 + (t0 + 64) * 2);
    }
    const char* kfbc = kfb + cur * BUFSZ;
    const char* vfbc = vfb + cur * BUFSZ;

    f32x4 sc[2][4] = {{zero, zero, zero, zero}, {zero, zero, zero, zero}};
    __builtin_amdgcn_s_setprio(1);
    #pragma unroll
    for (int ct = 0; ct < 4; ++ct) {
      FragU kf0, kf1;
      kf0.v = *(const bf16x8*)(kfbc + ct * 2304);
      kf1.v = *(const bf16x8*)(kfbc + ct * 2304 + 64);
      sc[0][ct] = MFMA16(kf0.v, qf[0][0].v, sc[0][ct]);
      sc[0][ct] = MFMA16(kf1.v, qf[0][1].v, sc[0][ct]);
      sc[1][ct] = MFMA16(kf0.v, qf[1][0].v, sc[1][ct]);
      sc[1][ct] = MFMA16(kf1.v, qf[1][1].v, sc[1][ct]);
    }
    __builtin_amdgcn_s_setprio(0);

    float lmax[2];
    #pragma unroll
    for (int qg = 0; qg < 2; ++qg) {
      float a0 = fmaxf(fmaxf(sc[qg][0][0], sc[qg][0][1]), fmaxf(sc[qg][0][2], sc[qg][0][3]));
      float a1 = fmaxf(fmaxf(sc[qg][1][0], sc[qg][1][1]), fmaxf(sc[qg][1][2], sc[qg][1][3]));
      float a2 = fmaxf(fmaxf(sc[qg][2][0], sc[qg][2][1]), fmaxf(sc[qg][2][2], sc[qg][2][3]));
      float a3 = fmaxf(fmaxf(sc[qg][3][0], sc[qg][3][1]), fmaxf(sc[qg][3][2], sc[qg][3][3]));
      lmax[qg] = fmaxf(fmaxf(a0, a1), fmaxf(a2, a3));
    }
    if (__any((lmax[0] - m_[0] > 8.f) || (lmax[1] - m_[1] > 8.f))) {
      #pragma unroll
      for (int qg = 0; qg < 2; ++qg) {
        float mm = lmax[qg];
        mm = fmaxf(mm, __shfl_xor(mm, 16));
        mm = fmaxf(mm, __shfl_xor(mm, 32));
        const float mn = fmaxf(m_[qg], mm);
        const float al = fexp2(m_[qg] - mn);
        m_[qg] = mn;
        l_[qg] *= al;
        float alr[4];
        #pragma unroll
        for (int r = 0; r < 4; ++r) alr[r] = __shfl(al, g * 4 + r);
        #pragma unroll
        for (int dt = 0; dt < 4; ++dt)
          #pragma unroll
          for (int r = 0; r < 4; ++r) accO[qg][dt][r] *= alr[r];
      }
    }

    FragU pf[2][2];
    #pragma unroll
    for (int qg = 0; qg < 2; ++qg) {
      #pragma unroll
      for (int ct = 0; ct < 4; ++ct)
        #pragma unroll
        for (int r = 0; r < 4; ++r)
          sc[qg][ct][r] = fexp2(sc[qg][ct][r] - m_[qg]);
      float s0 = (sc[qg][0][0] + sc[qg][0][1]) + (sc[qg][0][2] + sc[qg][0][3]);
      float s1 = (sc[qg][1][0] + sc[qg][1][1]) + (sc[qg][1][2] + sc[qg][1][3]);
      float s2 = (sc[qg][2][0] + sc[qg][2][1]) + (sc[qg][2][2] + sc[qg][2][3]);
      float s3 = (sc[qg][3][0] + sc[qg][3][1]) + (sc[qg][3][2] + sc[qg][3][3]);
      l_[qg] += (s0 + s1) + (s2 + s3);
      #pragma unroll
      for (int tc = 0; tc < 2; ++tc) {
        asm("v_cvt_pk_bf16_f32 %0, %1, %2" : "=v"(pf[qg][tc].w[0]) : "v"(sc[qg][2*tc][0]),   "v"(sc[qg][2*tc][1]));
        asm("v_cvt_pk_bf16_f32 %0, %1, %2" : "=v"(pf[qg][tc].w[1]) : "v"(sc[qg][2*tc][2]),   "v"(sc[qg][2*tc][3]));
        asm("v_cvt_pk_bf16_f32 %0, %1, %2" : "=v"(pf[qg][tc].w[2]) : "v"(sc[qg][2*tc+1][0]), "v"(sc[qg][2*tc+1][1]));
        asm("v_cvt_pk_bf16_f32 %0, %1, %2" : "=v"(pf[qg][tc].w[3]) : "v"(sc[qg][2*tc+1][2]), "v"(sc[qg][2*tc+1][3]));
      }
    }

    __builtin_amdgcn_s_setprio(1);
    #pragma unroll
    for (int dt = 0; dt < 4; ++dt) {
      FragU vf0, vf1;
      vf0.v = *(const bf16x8*)(vfbc + dt * 2304);
      vf1.v = *(const bf16x8*)(vfbc + dt * 2304 + 64);
      accO[0][dt] = MFMA16(pf[0][0].v, vf0.v, accO[0][dt]);
      accO[0][dt] = MFMA16(pf[0][1].v, vf1.v, accO[0][dt]);
      accO[1][dt] = MFMA16(pf[1][0].v, vf0.v, accO[1][dt]);
      accO[1][dt] = MFMA16(pf[1][1].v, vf1.v, accO[1][dt]);
    }
    __builtin_amdgcn_s_setprio(0);

    if (hasNext) {
      const int nb = (cur ^ 1) * BUFSZ;
      *(uint4*)(kD0 + nb) = kA;
      *(uint4*)(vD0 + nb) = vA;
    }
    __syncthreads();
  }

  const int b = bh >> 4, h = bh & (H_ - 1);
  u16* basep = attP + (size_t)b * S_ * D_;
  #pragma unroll
  for (int qg = 0; qg < 2; ++qg) {
    float lt = l_[qg];
    lt += __shfl_xor(lt, 16);
    lt += __shfl_xor(lt, 32);
    #pragma unroll
    for (int r = 0; r < 4; ++r) {
      const int s = qbase + qg * 16 + g * 4 + r;
      u16* op = basep + (size_t)s * D_ + h * HD_;
      #pragma unroll
      for (int dt = 0; dt < 4; ++dt) op[dt * 16 + lr] = f2bf(accO[qg][dt][r]);
    }
    if (g == 0)
      lrow[((size_t)b * H_ + h) * S_ + qbase + qg * 16 + lr] = lt;
  }
  #undef BUFSZ
}

// ---------------------------------------------------------------------------
// combine (divide by l) + LayerNorm, bf16 partial input.
// ---------------------------------------------------------------------------
__global__ __launch_bounds__(256) void combine_ln_kernel(
    const u16* __restrict__ attP, const float* __restrict__ lrow,
    const float* __restrict__ gamma, const float* __restrict__ beta,
    float* __restrict__ out)
{
  const int row = blockIdx.x;          // b*S + s
  const int b = row >> 11, s = row & (S_ - 1);
  const int tid = threadIdx.x;
  const int h = tid >> 4;

  const float inv = 1.0f / lrow[((size_t)b * H_ + h) * S_ + s];
  union { uint2 d; u16 u[4]; } raw;
  raw.d = ((const uint2*)(attP + (size_t)row * D_))[tid];
  float4 x;
  x.x = __builtin_bit_cast(float, (unsigned)raw.u[0] << 16) * inv;
  x.y = __builtin_bit_cast(float, (unsigned)raw.u[1] << 16) * inv;
  x.z = __builtin_bit_cast(float, (unsigned)raw.u[2] << 16) * inv;
  x.w = __builtin_bit_cast(float, (unsigned)raw.u[3] << 16) * inv;

  float sm = x.x + x.y + x.z + x.w;
  float sq = x.x * x.x + x.y * x.y + x.z * x.z + x.w * x.w;
  #pragma unroll
  for (int j = 1; j < 64; j <<= 1) { sm += __shfl_xor(sm, j); sq += __shfl_xor(sq, j); }
  __shared__ float ls[4], lq[4];
  const int w = tid >> 6;
  if ((tid & 63) == 0) { ls[w] = sm; lq[w] = sq; }
  __syncthreads();
  if (tid == 0) {
    ls[0] = ls[0] + ls[1] + ls[2] + ls[3];
    lq[0] = lq[0] + lq[1] + lq[2] + lq[3];
  }
  __syncthreads();
  const float mean = ls[0] * (1.f / D_);
  const float var  = lq[0] * (1.f / D_) - mean * mean;
  const float rs = rsqrtf(var + 1e-5f);
  const float4 gv = ((const float4*)gamma)[tid];
  const float4 bv = ((const float4*)beta)[tid];
  float4 o;
  o.x = (x.x - mean) * rs * gv.x + bv.x;
  o.y = (x.y - mean) * rs * gv.y + bv.y;
  o.z = (x.z - mean) * rs * gv.z + bv.z;
  o.w = (x.w - mean) * rs * gv.w + bv.w;
  ((float4*)(out + (size_t)row * D_))[tid] = o;
}

extern "C" void kernel_launch(void* const* d_in, const int* in_sizes, int n_in,
                              void* d_out, int out_size, void* d_ws, size_t ws_size,
                              hipStream_t stream) {
  const float* queries = (const float*)d_in[0];
  const float* keys    = (const float*)d_in[1];
  const float* values  = (const float*)d_in[2];
  const float* Wq = (const float*)d_in[3];
  const float* bq = (const float*)d_in[4];
  const float* Wk = (const float*)d_in[5];
  const float* bk = (const float*)d_in[6];
  const float* Wv = (const float*)d_in[7];
  const float* bv = (const float*)d_in[8];
  const float* gamma = (const float*)d_in[9];
  const float* beta  = (const float*)d_in[10];
  float* out = (float*)d_out;

  const size_t PER = (size_t)B_ * H_ * S_ * HD_;          // 4,194,304 elems
  u16* q_ws  = (u16*)d_ws;                                // 8 MB
  u16* k_ws  = q_ws + PER;                                // 8 MB
  u16* vt_ws = k_ws + PER;                                // 8 MB
  u16* WT   = vt_ws + PER;                                // 6 MB, dead after proj
  u16* attP = vt_ws + PER;                                // aliases WT (8 MB)
  const size_t NOUT = (size_t)B_ * S_ * D_;
  float* lrow = (float*)(attP + NOUT);

  prep_kernel<<<dim3(192), 256, 0, stream>>>(Wq, Wk, Wv, WT);
  proj_kernel<<<dim3(32, 8, 3), 512, 0, stream>>>(
      queries, keys, values, WT, bq, bk, bv, q_ws, k_ws, vt_ws);
  attn_kernel<<<dim3(256), 512, 0, stream>>>(q_ws, k_ws, vt_ws, attP, lrow);
  combine_ln_kernel<<<dim3(4096), 256, 0, stream>>>(attP, lrow, gamma, beta, out);
}